// Round 8
// baseline (7208.424 us; speedup 1.0000x reference)
//
#include <hip/hip_runtime.h>

// ============================================================================
// 2-layer LSTM (B=64,T=512,D=256,H=1024) + linear, fp32.
// Persistent kernel, diagonal pipeline (phase p = L0 step p || L1 step p-1),
// int16 weights/acts split into two int8 planes, 3x i8-MFMA per K=32.
// R8 = R7 + per-XCD L2 staging of h with PROVEN sync only:
//   R7 post-mortem: sc0sc1 MALL path walls at ~3.8TB/s (48MB/phase redundant
//   h reads). Now each phase: all WGs copy h(p-1) once per XCD (rank-sliced,
//   XCC_ID HW-verified) MALL->local L2 scratch (plain stores; CDNA L1 is
//   write-through so data lands in the shared per-XCD L2), ordered by a
//   SECOND master-gather global barrier (no producer-consumer flags — the
//   R4/R6 failure class). Compute streams h from scratch with sc0 loads
//   (L1-bypass, local L2 hit) through R7's unchanged WAIT_BIND pipeline.
//   MALL bypass reads: 48MB -> 2MB/phase.
// Barrier gens: registration=1; phase p: wait 2p+1, copy, arrive 2p+2,
// wait 2p+2, compute, store h (sc0sc1), arrive 2p+3.
// ============================================================================

#define T_STEPS 512
#define NWG 256
#define LDS_W     131072                  // [64 ksteps][2 planes][64 lanes][16B]
#define LDS_GBUF  (64 * 33 * 4)           // 8448, padded stride 33
#define LDS_CBUF  (64 * 9 * 4)            // 2304, padded stride 9
#define LDS_OFFS  (32 * 4)
#define LDS_MISC  64
#define SMEM_BYTES (LDS_W + LDS_GBUF + LDS_CBUF + LDS_OFFS + LDS_MISC) // 142016
#define SCR_XCD   524288                  // per-XCD scratch: 2 slots x 256KB

typedef int v2i  __attribute__((ext_vector_type(2)));
typedef int v4i  __attribute__((ext_vector_type(4)));
typedef int v16i __attribute__((ext_vector_type(16)));

__device__ __forceinline__ v16i zero16() {
    v16i z;
#pragma unroll
    for (int i = 0; i < 16; ++i) z[i] = 0;
    return z;
}

__device__ __forceinline__ int get_xcd() {
    unsigned v;
    asm("s_getreg_b32 %0, hwreg(HW_REG_XCC_ID)" : "=s"(v));
    return (int)(v & 7);
}

// 16x global_load_dwordx4 sc0 (L1-bypass, served by local L2), NO trailing wait.
__device__ __forceinline__ void load_h16_l2(const short* base, v4i* o) {
    asm volatile(
        "global_load_dwordx4 %0, %16, off sc0\n\t"
        "global_load_dwordx4 %1, %16, off offset:16 sc0\n\t"
        "global_load_dwordx4 %2, %16, off offset:64 sc0\n\t"
        "global_load_dwordx4 %3, %16, off offset:80 sc0\n\t"
        "global_load_dwordx4 %4, %16, off offset:128 sc0\n\t"
        "global_load_dwordx4 %5, %16, off offset:144 sc0\n\t"
        "global_load_dwordx4 %6, %16, off offset:192 sc0\n\t"
        "global_load_dwordx4 %7, %16, off offset:208 sc0\n\t"
        "global_load_dwordx4 %8, %16, off offset:256 sc0\n\t"
        "global_load_dwordx4 %9, %16, off offset:272 sc0\n\t"
        "global_load_dwordx4 %10, %16, off offset:320 sc0\n\t"
        "global_load_dwordx4 %11, %16, off offset:336 sc0\n\t"
        "global_load_dwordx4 %12, %16, off offset:384 sc0\n\t"
        "global_load_dwordx4 %13, %16, off offset:400 sc0\n\t"
        "global_load_dwordx4 %14, %16, off offset:448 sc0\n\t"
        "global_load_dwordx4 %15, %16, off offset:464 sc0"
        : "=&v"(o[0]), "=&v"(o[1]), "=&v"(o[2]), "=&v"(o[3]),
          "=&v"(o[4]), "=&v"(o[5]), "=&v"(o[6]), "=&v"(o[7]),
          "=&v"(o[8]), "=&v"(o[9]), "=&v"(o[10]), "=&v"(o[11]),
          "=&v"(o[12]), "=&v"(o[13]), "=&v"(o[14]), "=&v"(o[15])
        : "v"(base)
        : "memory");
}

// s_waitcnt vmcnt(N) with buffer bound in/out (no hoisting past the wait).
#define WAIT_BIND(cntstr, b)                                                   \
    asm volatile("s_waitcnt vmcnt(" cntstr ")"                                 \
        : "+v"((b)[0]), "+v"((b)[1]), "+v"((b)[2]), "+v"((b)[3]),              \
          "+v"((b)[4]), "+v"((b)[5]), "+v"((b)[6]), "+v"((b)[7]),              \
          "+v"((b)[8]), "+v"((b)[9]), "+v"((b)[10]), "+v"((b)[11]),            \
          "+v"((b)[12]), "+v"((b)[13]), "+v"((b)[14]), "+v"((b)[15])           \
        :: "memory")

// copy 64B: MALL-fresh load (sc0 sc1) -> plain store (lands in local L2).
__device__ __forceinline__ void copy64(const char* src, char* dst) {
    v4i a, b, c, d;
    asm volatile(
        "global_load_dwordx4 %0, %4, off sc0 sc1\n\t"
        "global_load_dwordx4 %1, %4, off offset:16 sc0 sc1\n\t"
        "global_load_dwordx4 %2, %4, off offset:32 sc0 sc1\n\t"
        "global_load_dwordx4 %3, %4, off offset:48 sc0 sc1\n\t"
        "s_waitcnt vmcnt(0)\n\t"
        "global_store_dwordx4 %5, %0, off\n\t"
        "global_store_dwordx4 %5, %1, off offset:16\n\t"
        "global_store_dwordx4 %5, %2, off offset:32\n\t"
        "global_store_dwordx4 %5, %3, off offset:48"
        : "=&v"(a), "=&v"(b), "=&v"(c), "=&v"(d)
        : "v"(src), "v"(dst)
        : "memory");
}

__device__ __forceinline__ void store_h8(short* p, v2i v) {    // write-through MALL
    asm volatile("global_store_dwordx2 %0, %1, off sc0 sc1" :: "v"(p), "v"(v) : "memory");
}
__device__ __forceinline__ void waitcnt0() {
    asm volatile("s_waitcnt vmcnt(0)" ::: "memory");
}

__device__ __forceinline__ void split_a(v4i A0, v4i A1, v4i& HI, v4i& LO) {
    HI.x = (int)__builtin_amdgcn_perm((unsigned)A0.y, (unsigned)A0.x, 0x07050301u);
    HI.y = (int)__builtin_amdgcn_perm((unsigned)A0.w, (unsigned)A0.z, 0x07050301u);
    HI.z = (int)__builtin_amdgcn_perm((unsigned)A1.y, (unsigned)A1.x, 0x07050301u);
    HI.w = (int)__builtin_amdgcn_perm((unsigned)A1.w, (unsigned)A1.z, 0x07050301u);
    LO.x = (int)(__builtin_amdgcn_perm((unsigned)A0.y, (unsigned)A0.x, 0x06040200u) ^ 0x80808080u);
    LO.y = (int)(__builtin_amdgcn_perm((unsigned)A0.w, (unsigned)A0.z, 0x06040200u) ^ 0x80808080u);
    LO.z = (int)(__builtin_amdgcn_perm((unsigned)A1.y, (unsigned)A1.x, 0x06040200u) ^ 0x80808080u);
    LO.w = (int)(__builtin_amdgcn_perm((unsigned)A1.w, (unsigned)A1.z, 0x06040200u) ^ 0x80808080u);
}

// consume one 8-kstep batch from register buffer hb against weights at wbase
__device__ __forceinline__ void consume8(const v4i* hb, const char* wbase,
                                         v16i& ahh, v16i& amid)
{
#pragma unroll
    for (int s = 0; s < 8; ++s) {
        v4i HI, LO; split_a(hb[2 * s], hb[2 * s + 1], HI, LO);
        v4i BH = *(const v4i*)(wbase + s * 2048);
        v4i BL = *(const v4i*)(wbase + s * 2048 + 1024);
        ahh  = __builtin_amdgcn_mfma_i32_32x32x32_i8(HI, BH, ahh, 0, 0, 0);
        amid = __builtin_amdgcn_mfma_i32_32x32x32_i8(HI, BL, amid, 0, 0, 0);
        amid = __builtin_amdgcn_mfma_i32_32x32x32_i8(LO, BH, amid, 0, 0, 0);
    }
}

// plain cached-load kstep (x segment only)
__device__ __forceinline__ void kstep(const short* __restrict__ ap,
                                      const char* __restrict__ wl,
                                      v16i& ahh, v16i& amid)
{
    v4i A0 = *(const v4i*)ap;
    v4i A1 = *(const v4i*)(ap + 8);
    v4i HI, LO; split_a(A0, A1, HI, LO);
    v4i BH = *(const v4i*)wl;
    v4i BL = *(const v4i*)(wl + 1024);
    ahh  = __builtin_amdgcn_mfma_i32_32x32x32_i8(HI, BH, ahh, 0, 0, 0);
    amid = __builtin_amdgcn_mfma_i32_32x32x32_i8(HI, BL, amid, 0, 0, 0);
    amid = __builtin_amdgcn_mfma_i32_32x32x32_i8(LO, BH, amid, 0, 0, 0);
}

// ---------------------------------------------------------------------------
__global__ void quant_x(const float* __restrict__ x, short* __restrict__ xq, int n)
{
    int i = blockIdx.x * 256 + threadIdx.x;
    if (i < n) {
        float v = x[i] * 2048.f;
        v = fminf(fmaxf(v, -32767.f), 32767.f);
        xq[i] = (short)__float2int_rn(v);
    }
}

// prep: quantize + gate-reorder + fragment-tile weights into per-WG LDS images.
__global__ void quant_w(const float* __restrict__ wih0, const float* __restrict__ whh0,
                        const float* __restrict__ wih1, const float* __restrict__ whh1,
                        char* __restrict__ wimg)
{
    int gid = blockIdx.x * 256 + threadIdx.x;       // 256*64*64 = 1048576 threads
    if (gid >= 256 * 64 * 64) return;
    int lane = gid & 63;
    int s    = (gid >> 6) & 63;
    int wg   = gid >> 12;
    int layer = wg >> 7, nblk = wg & 127;
    int col = nblk * 32 + (lane & 31);
    int ro  = (col & 3) * 1024 + (col >> 2);        // original gate-blocked row
    int k0  = s * 32 + (lane >> 5) * 16;
    char* dst = wimg + (size_t)wg * LDS_W + s * 2048 + lane * 16;
#pragma unroll
    for (int j = 0; j < 16; ++j) {
        int k = k0 + j;
        float w = 0.f;
        if (layer == 0) {
            if (k < 256)       w = wih0[ro * 256 + k];
            else if (k < 1280) w = whh0[ro * 1024 + (k - 256)];
        } else {
            if (k < 1024)      w = wih1[ro * 1024 + k];
            else               w = whh1[ro * 1024 + (k - 1024)];
        }
        int q  = __float2int_rn(w * 524288.f);      // 2^19, |q|<=16384
        int hi = (q + 128) >> 8;
        int lo = q - (hi << 8);
        dst[j]        = (char)hi;
        dst[1024 + j] = (char)lo;
    }
}

// ---------------------------------------------------------------------------
__global__ void __launch_bounds__(128) lstm_main(
    const short* __restrict__ xq, const char* __restrict__ wimg,
    const float* __restrict__ bih0, const float* __restrict__ bhh0,
    const float* __restrict__ bih1, const float* __restrict__ bhh1,
    short* __restrict__ h0q, short* __restrict__ h2q,
    float* __restrict__ h2f, unsigned* gslots, unsigned* gbcast,
    unsigned* cntp, char* scratch)
{
    extern __shared__ char smem[];
    char*  wlds = smem;
    float* gbuf = (float*)(smem + LDS_W);                       // [64][33]
    float* cbuf = (float*)(smem + LDS_W + LDS_GBUF);            // [64][9]
    float* offs = (float*)(smem + LDS_W + LDS_GBUF + LDS_CBUF); // [32]
    int*   misc = (int*)(smem + LDS_W + LDS_GBUF + LDS_CBUF + LDS_OFFS);

    const int wg    = blockIdx.x;
    const int layer = wg >> 7;
    const int nblk  = wg & 127;
    const int tid   = threadIdx.x;
    const int lane  = tid & 63;
    const int xcd   = get_xcd();
    const float inv30 = 9.313225746154785e-10f;   // 2^-30
    const float inv33 = 1.1641532182693481e-10f;  // 2^-33

    // register residency on this physical XCD (cntp zeroed by host memset)
    if (tid == 0) misc[0] = (int)atomicAdd(cntp + xcd * 16, 1u);

    // stage this WG's weight image into LDS (128KB)
    {
        const v4i* src = (const v4i*)(wimg + (size_t)wg * LDS_W);
        v4i* dst = (v4i*)wlds;
        for (int i = tid; i < LDS_W / 16; i += 128) dst[i] = src[i];
    }
    for (int i = tid; i < 64 * 9; i += 128) cbuf[i] = 0.f;
    __syncthreads();
    const int rank = misc[0];

    // per-col constant: 128*colsum16*inv_scale (LO'=-128 bias comp) + gate bias
    if (tid < 32) {
        const int c  = tid;
        const int ns = (layer == 0) ? 40 : 64;
        int cs_x = 0, cs_h = 0;
        for (int s = 0; s < ns; ++s) {
            int sum = 0;
#pragma unroll
            for (int half = 0; half < 2; ++half) {
                const signed char* ph = (const signed char*)(wlds + s * 2048 + (half * 32 + c) * 16);
#pragma unroll
                for (int j = 0; j < 16; ++j)
                    sum += 256 * (int)ph[j] + (int)ph[1024 + j];
            }
            if (layer == 0 && s < 8) cs_x += sum; else cs_h += sum;
        }
        const int col = nblk * 32 + c;
        const int ro  = (col & 3) * 1024 + (col >> 2);
        const float bias = (layer == 0) ? (bih0[ro] + bhh0[ro]) : (bih1[ro] + bhh1[ro]);
        float off = 128.f * (float)cs_h * inv33 + bias;
        if (layer == 0) off += 128.f * (float)cs_x * inv30;
        offs[c] = off;
    }
    __syncthreads();
    // registration arrival (gen 1): makes cntp[] final before first copy
    if (tid == 0)
        __hip_atomic_store(gslots + wg * 16, 1u, __ATOMIC_RELAXED, __HIP_MEMORY_SCOPE_AGENT);

    const int mrow = (tid >> 6) * 32 + (lane & 31);   // batch row of A fragment
    const int ksub = (lane >> 5) * 16;                // k sub-offset (i16 units)
    int count = 0;

    for (int p = 0; p <= T_STEPS; ++p) {
        const bool active = (layer == 0) ? (p < T_STEPS) : (p >= 1);
        const int  slot   = (p + 1) & 1;
        char* scrS = scratch + (size_t)xcd * SCR_XCD + slot * 262144;

        // ---- L0 x-projection BEFORE the wait (independent of phase p-1) ---
        float px[16];
        if (layer == 0 && active) {
            v16i ax = zero16(), mx = zero16();
            const short* axp = xq + ((size_t)mrow * 512 + p) * 256 + ksub;
#pragma unroll
            for (int s = 0; s < 8; ++s)
                kstep(axp + s * 32, wlds + s * 2048 + lane * 16, ax, mx);
#pragma unroll
            for (int r = 0; r < 16; ++r)
                px[r] = ((float)ax[r] * 65536.f + (float)mx[r] * 256.f) * inv30;
        }

        // ---- W1: wait gen 2p+1 (p=0: registration; p>0: prior h stores) ---
        {
            const unsigned g = (unsigned)(2 * p + 1);
            if (wg == 0) {
                const unsigned* s0 = gslots + (tid * 2) * 16;
                const unsigned* s1 = s0 + 16;
                while (__hip_atomic_load(s0, __ATOMIC_RELAXED, __HIP_MEMORY_SCOPE_AGENT) < g)
                    __builtin_amdgcn_s_sleep(1);
                while (__hip_atomic_load(s1, __ATOMIC_RELAXED, __HIP_MEMORY_SCOPE_AGENT) < g)
                    __builtin_amdgcn_s_sleep(1);
                __syncthreads();
                __hip_atomic_store(gbcast + (tid * 2) * 16, g, __ATOMIC_RELAXED, __HIP_MEMORY_SCOPE_AGENT);
                __hip_atomic_store(gbcast + (tid * 2 + 1) * 16, g, __ATOMIC_RELAXED, __HIP_MEMORY_SCOPE_AGENT);
            } else if (tid == 0) {
                while (__hip_atomic_load(gbcast + wg * 16, __ATOMIC_RELAXED, __HIP_MEMORY_SCOPE_AGENT) < g)
                    __builtin_amdgcn_s_sleep(1);
            }
            __syncthreads();
            asm volatile("" ::: "memory");
        }
        if (p == 0)
            count = (int)__hip_atomic_load(cntp + xcd * 16, __ATOMIC_RELAXED, __HIP_MEMORY_SCOPE_AGENT);

        // ---- COPY: rank-sliced MALL -> local-XCD L2 scratch ---------------
        // 32 slices x 8KB = [h0 slot (128KB)][h2 slot (128KB)]
        for (int i = rank; i < 32; i += count) {
            const char* srcb = (i < 16)
                ? (const char*)h0q + slot * 131072 + i * 8192
                : (const char*)h2q + slot * 131072 + (i - 16) * 8192;
            copy64(srcb + tid * 64, scrS + i * 8192 + tid * 64);
        }
        // ---- arrive gen 2p+2 (copies drained) -----------------------------
        waitcnt0();
        __syncthreads();
        if (tid == 0)
            __hip_atomic_store(gslots + wg * 16, (unsigned)(2 * p + 2),
                               __ATOMIC_RELAXED, __HIP_MEMORY_SCOPE_AGENT);
        // ---- W2: wait gen 2p+2 (this XCD's scratch complete) --------------
        {
            const unsigned g = (unsigned)(2 * p + 2);
            if (wg == 0) {
                const unsigned* s0 = gslots + (tid * 2) * 16;
                const unsigned* s1 = s0 + 16;
                while (__hip_atomic_load(s0, __ATOMIC_RELAXED, __HIP_MEMORY_SCOPE_AGENT) < g)
                    __builtin_amdgcn_s_sleep(1);
                while (__hip_atomic_load(s1, __ATOMIC_RELAXED, __HIP_MEMORY_SCOPE_AGENT) < g)
                    __builtin_amdgcn_s_sleep(1);
                __syncthreads();
                __hip_atomic_store(gbcast + (tid * 2) * 16, g, __ATOMIC_RELAXED, __HIP_MEMORY_SCOPE_AGENT);
                __hip_atomic_store(gbcast + (tid * 2 + 1) * 16, g, __ATOMIC_RELAXED, __HIP_MEMORY_SCOPE_AGENT);
            } else if (tid == 0) {
                while (__hip_atomic_load(gbcast + wg * 16, __ATOMIC_RELAXED, __HIP_MEMORY_SCOPE_AGENT) < g)
                    __builtin_amdgcn_s_sleep(1);
            }
            __syncthreads();
            asm volatile("" ::: "memory");
        }

        if (active) {
            const short* hprev = (const short*)scrS + mrow * 1024 + ksub;           // h0(p-1)
            float gates[16];
            v16i ahh = zero16(), amid = zero16();
            v4i b0[16], b1[16];
            if (layer == 0) {
                // h segment (K=1024, ksteps 8..39), double-buffered from local L2
                if (p > 0) {
                    waitcnt0();
                    const char* W = wlds + lane * 16;
                    load_h16_l2(hprev, b0);
                    load_h16_l2(hprev + 256, b1);
                    WAIT_BIND("16", b0); consume8(b0, W + 8 * 2048, ahh, amid);
                    load_h16_l2(hprev + 512, b0);
                    WAIT_BIND("16", b1); consume8(b1, W + 16 * 2048, ahh, amid);
                    load_h16_l2(hprev + 768, b1);
                    WAIT_BIND("16", b0); consume8(b0, W + 24 * 2048, ahh, amid);
                    WAIT_BIND("0", b1);  consume8(b1, W + 32 * 2048, ahh, amid);
                }
#pragma unroll
                for (int r = 0; r < 16; ++r)
                    gates[r] = px[r]
                             + ((float)ahh[r] * 65536.f + (float)amid[r] * 256.f) * inv33
                             + offs[lane & 31];
            } else {
                // layer1: h0(p-1) (ksteps 0..31) then h2(p-2) (ksteps 32..63)
                const short* h2p = (const short*)(scrS + 131072) + mrow * 1024 + ksub;
                waitcnt0();
                const char* W = wlds + lane * 16;
                load_h16_l2(hprev, b0);
                load_h16_l2(hprev + 256, b1);
                WAIT_BIND("16", b0); consume8(b0, W, ahh, amid);
                load_h16_l2(hprev + 512, b0);
                WAIT_BIND("16", b1); consume8(b1, W + 8 * 2048, ahh, amid);
                load_h16_l2(hprev + 768, b1);
                WAIT_BIND("16", b0); consume8(b0, W + 16 * 2048, ahh, amid);
                load_h16_l2(h2p, b0);
                WAIT_BIND("16", b1); consume8(b1, W + 24 * 2048, ahh, amid);
                load_h16_l2(h2p + 256, b1);
                WAIT_BIND("16", b0); consume8(b0, W + 32 * 2048, ahh, amid);
                load_h16_l2(h2p + 512, b0);
                WAIT_BIND("16", b1); consume8(b1, W + 40 * 2048, ahh, amid);
                load_h16_l2(h2p + 768, b1);
                WAIT_BIND("16", b0); consume8(b0, W + 48 * 2048, ahh, amid);
                WAIT_BIND("0", b1);  consume8(b1, W + 56 * 2048, ahh, amid);
#pragma unroll
                for (int r = 0; r < 16; ++r)
                    gates[r] = ((float)ahh[r] * 65536.f + (float)amid[r] * 256.f) * inv33
                             + offs[lane & 31];
            }
            // scatter C/D frag to LDS: col=lane&31, row=(r&3)+8*(r>>2)+4*(lane>>5)
            {
                const int rbase = (tid >> 6) * 32 + 4 * (lane >> 5);
                const int c = lane & 31;
#pragma unroll
                for (int r = 0; r < 16; ++r) {
                    int row = rbase + (r & 3) + 8 * (r >> 2);
                    gbuf[row * 33 + c] = gates[r];
                }
            }
        }
        __syncthreads();
        if (active) {
            // state update: thread = (row, unit quad); one 8B MALL store each.
            short* hw = ((layer == 0) ? h0q : h2q) + (p & 1) * 65536;
            const int r    = tid & 63;
            const int half = tid >> 6;
            unsigned hq[4];
            float hf[4];
#pragma unroll
            for (int j = 0; j < 4; ++j) {
                const int u = half * 4 + j;
                const float gi = gbuf[r * 33 + 4 * u + 0];
                const float gf = gbuf[r * 33 + 4 * u + 1];
                const float gg = gbuf[r * 33 + 4 * u + 2];
                const float go = gbuf[r * 33 + 4 * u + 3];
                const float i_ = 1.f / (1.f + __expf(-gi));
                const float f_ = 1.f / (1.f + __expf(-gf));
                const float g_ = 1.f - 2.f / (__expf(2.f * gg) + 1.f);
                const float o_ = 1.f / (1.f + __expf(-go));
                float c_ = f_ * cbuf[r * 9 + u] + i_ * g_;
                cbuf[r * 9 + u] = c_;
                const float h_ = o_ * (1.f - 2.f / (__expf(2.f * c_) + 1.f));
                hq[j] = (unsigned)(unsigned short)(short)__float2int_rn(h_ * 16384.f);
                hf[j] = h_;
            }
            v2i pk;
            pk.x = (int)(hq[0] | (hq[1] << 16));
            pk.y = (int)(hq[2] | (hq[3] << 16));
            const int jg = nblk * 8 + half * 4;
            store_h8(hw + r * 1024 + jg, pk);
            if (layer == 1 && p == T_STEPS) {
#pragma unroll
                for (int j = 0; j < 4; ++j) h2f[r * 1024 + jg + j] = hf[j];
            }
        }
        // ---- arrive gen 2p+3 (h stores at MALL); skip after final phase ---
        if (p < T_STEPS) {
            waitcnt0();
            __syncthreads();
            if (tid == 0)
                __hip_atomic_store(gslots + wg * 16, (unsigned)(2 * p + 3),
                                   __ATOMIC_RELAXED, __HIP_MEMORY_SCOPE_AGENT);
        }
    }
}

// ---------------------------------------------------------------------------
__global__ void final_lin(const float* __restrict__ h2f, const float* __restrict__ wlin,
                          const float* __restrict__ blin, float* __restrict__ out)
{
    const int b = blockIdx.x;
    const int l = threadIdx.x;
    float s = 0.f;
    for (int j = l; j < 1024; j += 64) s += h2f[b * 1024 + j] * wlin[j];
#pragma unroll
    for (int off = 32; off; off >>= 1) s += __shfl_down(s, off);
    if (l == 0) out[b] = s + blin[0];
}

// ---------------------------------------------------------------------------
extern "C" void kernel_launch(void* const* d_in, const int* in_sizes, int n_in,
                              void* d_out, int out_size, void* d_ws, size_t ws_size,
                              hipStream_t stream)
{
    const float* x    = (const float*)d_in[0];
    const float* wih0 = (const float*)d_in[1];
    const float* whh0 = (const float*)d_in[2];
    const float* bih0 = (const float*)d_in[3];
    const float* bhh0 = (const float*)d_in[4];
    const float* wih1 = (const float*)d_in[5];
    const float* whh1 = (const float*)d_in[6];
    const float* bih1 = (const float*)d_in[7];
    const float* bhh1 = (const float*)d_in[8];
    const float* wlin = (const float*)d_in[9];
    const float* blin = (const float*)d_in[10];

    // workspace layout (R7's + cntp + scratch)
    char* ws = (char*)d_ws;
    unsigned* gslots = (unsigned*)ws;                    // 256 x 64B
    unsigned* gbcast = (unsigned*)(ws + 16384);          // 256 x 64B
    unsigned* cntp   = (unsigned*)(ws + 32768);          // 8 x 64B
    short* h0q = (short*)(ws + 65536);                   // [2][64][1024] i16 = 256KB
    short* h2q = (short*)(ws + 65536 + 262144);          // 256KB
    float* h2f = (float*)(ws + 65536 + 524288);          // [64][1024] f32 = 256KB
    short* xq  = (short*)(ws + 65536 + 786432);          // 16MB
    char*  wimg = ws + 65536 + 786432 + 16777216;        // 256 * 128KB = 32MB
    char*  scratch = wimg + (size_t)256 * 131072;        // 8 XCD x 512KB = 4MB

    // zero barrier state + counters + h ping-pong buffers
    hipMemsetAsync(ws, 0, 65536 + 524288, stream);

    quant_x<<<32768, 256, 0, stream>>>(x, xq, 64 * 512 * 256);
    quant_w<<<4096, 256, 0, stream>>>(wih0, whh0, wih1, whh1, wimg);

    hipFuncSetAttribute((const void*)lstm_main,
        hipFuncAttributeMaxDynamicSharedMemorySize, SMEM_BYTES);

    lstm_main<<<NWG, 128, SMEM_BYTES, stream>>>(xq, wimg, bih0, bhh0, bih1, bhh1,
                                                h0q, h2q, h2f, gslots, gbcast,
                                                cntp, scratch);
    final_lin<<<64, 64, 0, stream>>>(h2f, wlin, blin, (float*)d_out);
}

// Round 9
// 7134.206 us; speedup vs baseline: 1.0104x; 1.0104x over previous
//
#include <hip/hip_runtime.h>

// ============================================================================
// 2-layer LSTM (B=64,T=512,D=256,H=1024) + linear, fp32.
// Persistent kernel, diagonal pipeline, int16 weights/acts split into two
// int8 planes, 3x i8-MFMA per K=32. (R7 compute core, proven 6.4ms.)
// R9: barrier topology rebuild.
//  - Packed all-gather: 256 arrival slots at 4B stride (16 lines). Poll =
//    one dwordx4/lane over 64 lanes + __ballot. One-hop chain (~2us) vs
//    master-gather's two hops (~4us). Slot stores are plain disjoint dword
//    sc0sc1 write-throughs (R1's pathology was atomic RMW, not stores).
//  - Dual-circuit lag: h0 on a 4-slot ring. L0 waits {L0>=p, L1>=p-2};
//    L1 waits {L0>=p, L1>=p}. Since only L1 consumes L0 data, L0 (lighter:
//    64KB less streaming + x-proj overlap) runs up to 2 phases ahead, making
//    L1's wait on L0 pre-satisfied; critical path = one layer's cycle.
//    Deadlock-safe: if all WGs completed phase p-1 (slots=p), L0's and L1's
//    conditions both hold at phase p -> all arrive p+1. Ring safety: L0
//    writing h0(p) (slot p&3) overwrites h0(p-4), whose last reader (L1
//    phase p-3) is covered by L1>=p-2.
// ============================================================================

#define T_STEPS 512
#define NWG 256
#define LDS_W     131072                  // [64 ksteps][2 planes][64 lanes][16B]
#define LDS_GBUF  (64 * 33 * 4)           // 8448, padded stride 33
#define LDS_CBUF  (64 * 9 * 4)            // 2304, padded stride 9
#define LDS_OFFS  (32 * 4)
#define SMEM_BYTES (LDS_W + LDS_GBUF + LDS_CBUF + LDS_OFFS)   // 141952

typedef int v2i  __attribute__((ext_vector_type(2)));
typedef int v4i  __attribute__((ext_vector_type(4)));
typedef int v16i __attribute__((ext_vector_type(16)));

__device__ __forceinline__ v16i zero16() {
    v16i z;
#pragma unroll
    for (int i = 0; i < 16; ++i) z[i] = 0;
    return z;
}

// 16x global_load_dwordx4 sc0 sc1 (MALL-direct), NO trailing wait.
__device__ __forceinline__ void load_h16_nw(const short* base, v4i* o) {
    asm volatile(
        "global_load_dwordx4 %0, %16, off sc0 sc1\n\t"
        "global_load_dwordx4 %1, %16, off offset:16 sc0 sc1\n\t"
        "global_load_dwordx4 %2, %16, off offset:64 sc0 sc1\n\t"
        "global_load_dwordx4 %3, %16, off offset:80 sc0 sc1\n\t"
        "global_load_dwordx4 %4, %16, off offset:128 sc0 sc1\n\t"
        "global_load_dwordx4 %5, %16, off offset:144 sc0 sc1\n\t"
        "global_load_dwordx4 %6, %16, off offset:192 sc0 sc1\n\t"
        "global_load_dwordx4 %7, %16, off offset:208 sc0 sc1\n\t"
        "global_load_dwordx4 %8, %16, off offset:256 sc0 sc1\n\t"
        "global_load_dwordx4 %9, %16, off offset:272 sc0 sc1\n\t"
        "global_load_dwordx4 %10, %16, off offset:320 sc0 sc1\n\t"
        "global_load_dwordx4 %11, %16, off offset:336 sc0 sc1\n\t"
        "global_load_dwordx4 %12, %16, off offset:384 sc0 sc1\n\t"
        "global_load_dwordx4 %13, %16, off offset:400 sc0 sc1\n\t"
        "global_load_dwordx4 %14, %16, off offset:448 sc0 sc1\n\t"
        "global_load_dwordx4 %15, %16, off offset:464 sc0 sc1"
        : "=&v"(o[0]), "=&v"(o[1]), "=&v"(o[2]), "=&v"(o[3]),
          "=&v"(o[4]), "=&v"(o[5]), "=&v"(o[6]), "=&v"(o[7]),
          "=&v"(o[8]), "=&v"(o[9]), "=&v"(o[10]), "=&v"(o[11]),
          "=&v"(o[12]), "=&v"(o[13]), "=&v"(o[14]), "=&v"(o[15])
        : "v"(base)
        : "memory");
}

#define WAIT_BIND(cntstr, b)                                                   \
    asm volatile("s_waitcnt vmcnt(" cntstr ")"                                 \
        : "+v"((b)[0]), "+v"((b)[1]), "+v"((b)[2]), "+v"((b)[3]),              \
          "+v"((b)[4]), "+v"((b)[5]), "+v"((b)[6]), "+v"((b)[7]),              \
          "+v"((b)[8]), "+v"((b)[9]), "+v"((b)[10]), "+v"((b)[11]),            \
          "+v"((b)[12]), "+v"((b)[13]), "+v"((b)[14]), "+v"((b)[15])           \
        :: "memory")

__device__ __forceinline__ void store_h8(short* p, v2i v) {    // write-through MALL
    asm volatile("global_store_dwordx2 %0, %1, off sc0 sc1" :: "v"(p), "v"(v) : "memory");
}
__device__ __forceinline__ void store_slot(unsigned* p, unsigned v) {
    asm volatile("global_store_dword %0, %1, off sc0 sc1" :: "v"(p), "v"(v) : "memory");
}
__device__ __forceinline__ v4i ld4_mall(const unsigned* p) {
    v4i r;
    asm volatile("global_load_dwordx4 %0, %1, off sc0 sc1\n\ts_waitcnt vmcnt(0)"
                 : "=v"(r) : "v"(p) : "memory");
    return r;
}
__device__ __forceinline__ void waitcnt0() {
    asm volatile("s_waitcnt vmcnt(0)" ::: "memory");
}

__device__ __forceinline__ void split_a(v4i A0, v4i A1, v4i& HI, v4i& LO) {
    HI.x = (int)__builtin_amdgcn_perm((unsigned)A0.y, (unsigned)A0.x, 0x07050301u);
    HI.y = (int)__builtin_amdgcn_perm((unsigned)A0.w, (unsigned)A0.z, 0x07050301u);
    HI.z = (int)__builtin_amdgcn_perm((unsigned)A1.y, (unsigned)A1.x, 0x07050301u);
    HI.w = (int)__builtin_amdgcn_perm((unsigned)A1.w, (unsigned)A1.z, 0x07050301u);
    LO.x = (int)(__builtin_amdgcn_perm((unsigned)A0.y, (unsigned)A0.x, 0x06040200u) ^ 0x80808080u);
    LO.y = (int)(__builtin_amdgcn_perm((unsigned)A0.w, (unsigned)A0.z, 0x06040200u) ^ 0x80808080u);
    LO.z = (int)(__builtin_amdgcn_perm((unsigned)A1.y, (unsigned)A1.x, 0x06040200u) ^ 0x80808080u);
    LO.w = (int)(__builtin_amdgcn_perm((unsigned)A1.w, (unsigned)A1.z, 0x06040200u) ^ 0x80808080u);
}

__device__ __forceinline__ void consume8(const v4i* hb, const char* wbase,
                                         v16i& ahh, v16i& amid)
{
#pragma unroll
    for (int s = 0; s < 8; ++s) {
        v4i HI, LO; split_a(hb[2 * s], hb[2 * s + 1], HI, LO);
        v4i BH = *(const v4i*)(wbase + s * 2048);
        v4i BL = *(const v4i*)(wbase + s * 2048 + 1024);
        ahh  = __builtin_amdgcn_mfma_i32_32x32x32_i8(HI, BH, ahh, 0, 0, 0);
        amid = __builtin_amdgcn_mfma_i32_32x32x32_i8(HI, BL, amid, 0, 0, 0);
        amid = __builtin_amdgcn_mfma_i32_32x32x32_i8(LO, BH, amid, 0, 0, 0);
    }
}

// plain cached-load kstep (x segment only)
__device__ __forceinline__ void kstep(const short* __restrict__ ap,
                                      const char* __restrict__ wl,
                                      v16i& ahh, v16i& amid)
{
    v4i A0 = *(const v4i*)ap;
    v4i A1 = *(const v4i*)(ap + 8);
    v4i HI, LO; split_a(A0, A1, HI, LO);
    v4i BH = *(const v4i*)wl;
    v4i BL = *(const v4i*)(wl + 1024);
    ahh  = __builtin_amdgcn_mfma_i32_32x32x32_i8(HI, BH, ahh, 0, 0, 0);
    amid = __builtin_amdgcn_mfma_i32_32x32x32_i8(HI, BL, amid, 0, 0, 0);
    amid = __builtin_amdgcn_mfma_i32_32x32x32_i8(LO, BH, amid, 0, 0, 0);
}

// ---------------------------------------------------------------------------
__global__ void quant_x(const float* __restrict__ x, short* __restrict__ xq, int n)
{
    int i = blockIdx.x * 256 + threadIdx.x;
    if (i < n) {
        float v = x[i] * 2048.f;
        v = fminf(fmaxf(v, -32767.f), 32767.f);
        xq[i] = (short)__float2int_rn(v);
    }
}

// prep: quantize + gate-reorder + fragment-tile weights into per-WG LDS images.
__global__ void quant_w(const float* __restrict__ wih0, const float* __restrict__ whh0,
                        const float* __restrict__ wih1, const float* __restrict__ whh1,
                        char* __restrict__ wimg)
{
    int gid = blockIdx.x * 256 + threadIdx.x;       // 256*64*64 = 1048576 threads
    if (gid >= 256 * 64 * 64) return;
    int lane = gid & 63;
    int s    = (gid >> 6) & 63;
    int wg   = gid >> 12;
    int layer = wg >> 7, nblk = wg & 127;
    int col = nblk * 32 + (lane & 31);
    int ro  = (col & 3) * 1024 + (col >> 2);        // original gate-blocked row
    int k0  = s * 32 + (lane >> 5) * 16;
    char* dst = wimg + (size_t)wg * LDS_W + s * 2048 + lane * 16;
#pragma unroll
    for (int j = 0; j < 16; ++j) {
        int k = k0 + j;
        float w = 0.f;
        if (layer == 0) {
            if (k < 256)       w = wih0[ro * 256 + k];
            else if (k < 1280) w = whh0[ro * 1024 + (k - 256)];
        } else {
            if (k < 1024)      w = wih1[ro * 1024 + k];
            else               w = whh1[ro * 1024 + (k - 1024)];
        }
        int q  = __float2int_rn(w * 524288.f);      // 2^19, |q|<=16384
        int hi = (q + 128) >> 8;
        int lo = q - (hi << 8);
        dst[j]        = (char)hi;
        dst[1024 + j] = (char)lo;
    }
}

// ---------------------------------------------------------------------------
__global__ void __launch_bounds__(128) lstm_main(
    const short* __restrict__ xq, const char* __restrict__ wimg,
    const float* __restrict__ bih0, const float* __restrict__ bhh0,
    const float* __restrict__ bih1, const float* __restrict__ bhh1,
    short* __restrict__ h0q, short* __restrict__ h2q,
    float* __restrict__ h2f, unsigned* gslots)
{
    extern __shared__ char smem[];
    char*  wlds = smem;
    float* gbuf = (float*)(smem + LDS_W);                       // [64][33]
    float* cbuf = (float*)(smem + LDS_W + LDS_GBUF);            // [64][9]
    float* offs = (float*)(smem + LDS_W + LDS_GBUF + LDS_CBUF); // [32]

    const int wg    = blockIdx.x;
    const int layer = wg >> 7;
    const int nblk  = wg & 127;
    const int tid   = threadIdx.x;
    const int lane  = tid & 63;
    const float inv30 = 9.313225746154785e-10f;   // 2^-30
    const float inv33 = 1.1641532182693481e-10f;  // 2^-33

    // stage this WG's weight image into LDS (128KB)
    {
        const v4i* src = (const v4i*)(wimg + (size_t)wg * LDS_W);
        v4i* dst = (v4i*)wlds;
        for (int i = tid; i < LDS_W / 16; i += 128) dst[i] = src[i];
    }
    for (int i = tid; i < 64 * 9; i += 128) cbuf[i] = 0.f;
    __syncthreads();

    // per-col constant: 128*colsum16*inv_scale (LO'=-128 bias comp) + gate bias
    if (tid < 32) {
        const int c  = tid;
        const int ns = (layer == 0) ? 40 : 64;
        int cs_x = 0, cs_h = 0;
        for (int s = 0; s < ns; ++s) {
            int sum = 0;
#pragma unroll
            for (int half = 0; half < 2; ++half) {
                const signed char* ph = (const signed char*)(wlds + s * 2048 + (half * 32 + c) * 16);
#pragma unroll
                for (int j = 0; j < 16; ++j)
                    sum += 256 * (int)ph[j] + (int)ph[1024 + j];
            }
            if (layer == 0 && s < 8) cs_x += sum; else cs_h += sum;
        }
        const int col = nblk * 32 + c;
        const int ro  = (col & 3) * 1024 + (col >> 2);
        const float bias = (layer == 0) ? (bih0[ro] + bhh0[ro]) : (bih1[ro] + bhh1[ro]);
        float off = 128.f * (float)cs_h * inv33 + bias;
        if (layer == 0) off += 128.f * (float)cs_x * inv30;
        offs[c] = off;
    }
    __syncthreads();

    const int mrow = (tid >> 6) * 32 + (lane & 31);   // batch row of A fragment
    const int ksub = (lane >> 5) * 16;                // k sub-offset (i16 units)

    for (int p = 0; p <= T_STEPS; ++p) {
        const bool active = (layer == 0) ? (p < T_STEPS) : (p >= 1);

        // ---- L0 x-projection BEFORE the wait (independent of phase p-1) ---
        float px[16];
        if (layer == 0 && active) {
            v16i ax = zero16(), mx = zero16();
            const short* axp = xq + ((size_t)mrow * 512 + p) * 256 + ksub;
#pragma unroll
            for (int s = 0; s < 8; ++s)
                kstep(axp + s * 32, wlds + s * 2048 + lane * 16, ax, mx);
#pragma unroll
            for (int r = 0; r < 16; ++r)
                px[r] = ((float)ax[r] * 65536.f + (float)mx[r] * 256.f) * inv30;
        }

        // ---- packed all-gather wait (one hop) -----------------------------
        // L0 WG: slots[0..127] >= p, slots[128..255] >= p-2 (ring slack).
        // L1 WG: all slots >= p.
        if (p > 0) {
            if (tid < 64) {
                const unsigned thr0 = (unsigned)p;
                const unsigned thr1 = (layer == 0) ? (unsigned)(p > 2 ? p - 2 : 0)
                                                   : (unsigned)p;
                const unsigned thr = (tid < 32) ? thr0 : thr1;
                const unsigned* sp = gslots + tid * 4;
                for (;;) {
                    v4i v = ld4_mall(sp);
                    bool ok = ((unsigned)v.x >= thr) && ((unsigned)v.y >= thr) &&
                              ((unsigned)v.z >= thr) && ((unsigned)v.w >= thr);
                    if (!__ballot(!ok)) break;
                    __builtin_amdgcn_s_sleep(1);
                }
            }
            __syncthreads();
            asm volatile("" ::: "memory");
        }

        if (active) {
            const short* hprev = h0q + ((p + 3) & 3) * 65536 + mrow * 1024 + ksub; // h0(p-1)
            float gates[16];
            v16i ahh = zero16(), amid = zero16();
            v4i b0[16], b1[16];
            if (layer == 0) {
                // h segment (K=1024, ksteps 8..39), double-buffered pipeline
                if (p > 0) {
                    waitcnt0();   // drain stray vmcnt before counting
                    const char* W = wlds + lane * 16;
                    load_h16_nw(hprev, b0);
                    load_h16_nw(hprev + 256, b1);
                    WAIT_BIND("16", b0); consume8(b0, W + 8 * 2048, ahh, amid);
                    load_h16_nw(hprev + 512, b0);
                    WAIT_BIND("16", b1); consume8(b1, W + 16 * 2048, ahh, amid);
                    load_h16_nw(hprev + 768, b1);
                    WAIT_BIND("16", b0); consume8(b0, W + 24 * 2048, ahh, amid);
                    WAIT_BIND("0", b1);  consume8(b1, W + 32 * 2048, ahh, amid);
                }
#pragma unroll
                for (int r = 0; r < 16; ++r)
                    gates[r] = px[r]
                             + ((float)ahh[r] * 65536.f + (float)amid[r] * 256.f) * inv33
                             + offs[lane & 31];
            } else {
                // layer1: h0(p-1) (ksteps 0..31) then h2(p-2) (ksteps 32..63)
                const short* h2p = h2q + ((p + 1) & 1) * 65536 + mrow * 1024 + ksub;
                waitcnt0();
                const char* W = wlds + lane * 16;
                load_h16_nw(hprev, b0);
                load_h16_nw(hprev + 256, b1);
                WAIT_BIND("16", b0); consume8(b0, W, ahh, amid);
                load_h16_nw(hprev + 512, b0);
                WAIT_BIND("16", b1); consume8(b1, W + 8 * 2048, ahh, amid);
                load_h16_nw(hprev + 768, b1);
                WAIT_BIND("16", b0); consume8(b0, W + 16 * 2048, ahh, amid);
                load_h16_nw(h2p, b0);
                WAIT_BIND("16", b1); consume8(b1, W + 24 * 2048, ahh, amid);
                load_h16_nw(h2p + 256, b1);
                WAIT_BIND("16", b0); consume8(b0, W + 32 * 2048, ahh, amid);
                load_h16_nw(h2p + 512, b0);
                WAIT_BIND("16", b1); consume8(b1, W + 40 * 2048, ahh, amid);
                load_h16_nw(h2p + 768, b1);
                WAIT_BIND("16", b0); consume8(b0, W + 48 * 2048, ahh, amid);
                WAIT_BIND("0", b1);  consume8(b1, W + 56 * 2048, ahh, amid);
#pragma unroll
                for (int r = 0; r < 16; ++r)
                    gates[r] = ((float)ahh[r] * 65536.f + (float)amid[r] * 256.f) * inv33
                             + offs[lane & 31];
            }
            // scatter C/D frag to LDS: col=lane&31, row=(r&3)+8*(r>>2)+4*(lane>>5)
            {
                const int rbase = (tid >> 6) * 32 + 4 * (lane >> 5);
                const int c = lane & 31;
#pragma unroll
                for (int r = 0; r < 16; ++r) {
                    int row = rbase + (r & 3) + 8 * (r >> 2);
                    gbuf[row * 33 + c] = gates[r];
                }
            }
        }
        __syncthreads();
        if (active) {
            // state update: thread = (row, unit quad); one 8B MALL store each.
            short* hw = (layer == 0) ? h0q + (p & 3) * 65536
                                     : h2q + (p & 1) * 65536;
            const int r    = tid & 63;
            const int half = tid >> 6;
            unsigned hq[4];
            float hf[4];
#pragma unroll
            for (int j = 0; j < 4; ++j) {
                const int u = half * 4 + j;
                const float gi = gbuf[r * 33 + 4 * u + 0];
                const float gf = gbuf[r * 33 + 4 * u + 1];
                const float gg = gbuf[r * 33 + 4 * u + 2];
                const float go = gbuf[r * 33 + 4 * u + 3];
                const float i_ = 1.f / (1.f + __expf(-gi));
                const float f_ = 1.f / (1.f + __expf(-gf));
                const float g_ = 1.f - 2.f / (__expf(2.f * gg) + 1.f);
                const float o_ = 1.f / (1.f + __expf(-go));
                float c_ = f_ * cbuf[r * 9 + u] + i_ * g_;
                cbuf[r * 9 + u] = c_;
                const float h_ = o_ * (1.f - 2.f / (__expf(2.f * c_) + 1.f));
                hq[j] = (unsigned)(unsigned short)(short)__float2int_rn(h_ * 16384.f);
                hf[j] = h_;
            }
            v2i pk;
            pk.x = (int)(hq[0] | (hq[1] << 16));
            pk.y = (int)(hq[2] | (hq[3] << 16));
            const int jg = nblk * 8 + half * 4;
            store_h8(hw + r * 1024 + jg, pk);
            if (layer == 1 && p == T_STEPS) {
#pragma unroll
                for (int j = 0; j < 4; ++j) h2f[r * 1024 + jg + j] = hf[j];
            }
        }
        // ---- arrival (value p+1); skip after the final phase --------------
        if (p < T_STEPS) {
            waitcnt0();
            __syncthreads();
            if (tid == 0)
                store_slot(gslots + wg, (unsigned)(p + 1));
        }
    }
}

// ---------------------------------------------------------------------------
__global__ void final_lin(const float* __restrict__ h2f, const float* __restrict__ wlin,
                          const float* __restrict__ blin, float* __restrict__ out)
{
    const int b = blockIdx.x;
    const int l = threadIdx.x;
    float s = 0.f;
    for (int j = l; j < 1024; j += 64) s += h2f[b * 1024 + j] * wlin[j];
#pragma unroll
    for (int off = 32; off; off >>= 1) s += __shfl_down(s, off);
    if (l == 0) out[b] = s + blin[0];
}

// ---------------------------------------------------------------------------
extern "C" void kernel_launch(void* const* d_in, const int* in_sizes, int n_in,
                              void* d_out, int out_size, void* d_ws, size_t ws_size,
                              hipStream_t stream)
{
    const float* x    = (const float*)d_in[0];
    const float* wih0 = (const float*)d_in[1];
    const float* whh0 = (const float*)d_in[2];
    const float* bih0 = (const float*)d_in[3];
    const float* bhh0 = (const float*)d_in[4];
    const float* wih1 = (const float*)d_in[5];
    const float* whh1 = (const float*)d_in[6];
    const float* bih1 = (const float*)d_in[7];
    const float* bhh1 = (const float*)d_in[8];
    const float* wlin = (const float*)d_in[9];
    const float* blin = (const float*)d_in[10];

    // workspace layout
    char* ws = (char*)d_ws;
    unsigned* gslots = (unsigned*)ws;                    // 256 x 4B packed
    short* h0q = (short*)(ws + 65536);                   // [4][64][1024] i16 = 512KB ring
    short* h2q = (short*)(ws + 65536 + 524288);          // [2][64][1024] i16 = 256KB
    float* h2f = (float*)(ws + 65536 + 786432);          // [64][1024] f32 = 256KB
    short* xq  = (short*)(ws + 65536 + 1048576);         // 16MB
    char*  wimg = ws + 65536 + 1048576 + 16777216;       // 256 * 128KB = 32MB

    // zero slots + h rings (ws re-poisoned 0xAA each call)
    hipMemsetAsync(ws, 0, 65536 + 786432, stream);

    quant_x<<<32768, 256, 0, stream>>>(x, xq, 64 * 512 * 256);
    quant_w<<<4096, 256, 0, stream>>>(wih0, whh0, wih1, whh1, wimg);

    hipFuncSetAttribute((const void*)lstm_main,
        hipFuncAttributeMaxDynamicSharedMemorySize, SMEM_BYTES);

    lstm_main<<<NWG, 128, SMEM_BYTES, stream>>>(xq, wimg, bih0, bhh0, bih1, bhh1,
                                                h0q, h2q, h2f, gslots);
    final_lin<<<64, 64, 0, stream>>>(h2f, wlin, blin, (float*)d_out);
}

// Round 10
// 4823.631 us; speedup vs baseline: 1.4944x; 1.4790x over previous
//
#include <hip/hip_runtime.h>

// ============================================================================
// 2-layer LSTM (B=64,T=512,D=256,H=1024) + linear, fp32.
// Persistent kernel, diagonal pipeline (phase p = L0 step p || L1 step p-1),
// int16 weights/acts split into two int8 planes, 3x i8-MFMA per K=32.
// R10 = R7 (proven 6.4ms: master-gather barrier + WAIT_BIND double-buffered
// MALL loads) + FRAGMENT-NATIVE h layout:
//   h stored as [rowblock RB][kstep s][lane][32B] where, for element (row,k):
//   RB=row>>5, s=k>>5, lane=(row&31)+32*((k>>4)&1), inner=k&15. This makes
//   every consumer dwordx4 lane-contiguous (1KB): 4 lanes per 64B line, each
//   line requested ONCE (old row-major: 2 lanes/line, every line requested
//   twice by the offset-pair). Producer stores: one 16B chunk per row (vs 8B
//   scattered). Total MALL line-requests per phase halve. R3-R9 post-mortems
//   triangulate the load wall as request-rate-bound, so this targets it
//   without touching bytes, math, or sync.
// ============================================================================

#define T_STEPS 512
#define NWG 256
#define LDS_W     131072                  // [64 ksteps][2 planes][64 lanes][16B]
#define LDS_GBUF  (64 * 33 * 4)           // 8448, padded stride 33
#define LDS_CBUF  (64 * 9 * 4)            // 2304, padded stride 9
#define LDS_OFFS  (32 * 4)
#define SMEM_BYTES (LDS_W + LDS_GBUF + LDS_CBUF + LDS_OFFS)   // 141952

typedef int v2i  __attribute__((ext_vector_type(2)));
typedef int v4i  __attribute__((ext_vector_type(4)));
typedef int v16i __attribute__((ext_vector_type(16)));

__device__ __forceinline__ v16i zero16() {
    v16i z;
#pragma unroll
    for (int i = 0; i < 16; ++i) z[i] = 0;
    return z;
}

// One 8-kstep batch from fragment layout: 16 lane-contiguous dwordx4
// (sc0 sc1, MALL-direct), NO trailing wait. base = slot + RB*65536 +
// batch*16384 + lane*32 (bytes). kstep s at +s*2048, A0/A1 at +0/+16.
__device__ __forceinline__ void load_f16_nw(const char* b0p, v4i* o) {
    const char* b1p = b0p + 4096;
    const char* b2p = b0p + 8192;
    const char* b3p = b0p + 12288;
    asm volatile(
        "global_load_dwordx4 %0, %16, off sc0 sc1\n\t"
        "global_load_dwordx4 %1, %16, off offset:16 sc0 sc1\n\t"
        "global_load_dwordx4 %2, %16, off offset:2048 sc0 sc1\n\t"
        "global_load_dwordx4 %3, %16, off offset:2064 sc0 sc1\n\t"
        "global_load_dwordx4 %4, %17, off sc0 sc1\n\t"
        "global_load_dwordx4 %5, %17, off offset:16 sc0 sc1\n\t"
        "global_load_dwordx4 %6, %17, off offset:2048 sc0 sc1\n\t"
        "global_load_dwordx4 %7, %17, off offset:2064 sc0 sc1\n\t"
        "global_load_dwordx4 %8, %18, off sc0 sc1\n\t"
        "global_load_dwordx4 %9, %18, off offset:16 sc0 sc1\n\t"
        "global_load_dwordx4 %10, %18, off offset:2048 sc0 sc1\n\t"
        "global_load_dwordx4 %11, %18, off offset:2064 sc0 sc1\n\t"
        "global_load_dwordx4 %12, %19, off sc0 sc1\n\t"
        "global_load_dwordx4 %13, %19, off offset:16 sc0 sc1\n\t"
        "global_load_dwordx4 %14, %19, off offset:2048 sc0 sc1\n\t"
        "global_load_dwordx4 %15, %19, off offset:2064 sc0 sc1"
        : "=&v"(o[0]), "=&v"(o[1]), "=&v"(o[2]), "=&v"(o[3]),
          "=&v"(o[4]), "=&v"(o[5]), "=&v"(o[6]), "=&v"(o[7]),
          "=&v"(o[8]), "=&v"(o[9]), "=&v"(o[10]), "=&v"(o[11]),
          "=&v"(o[12]), "=&v"(o[13]), "=&v"(o[14]), "=&v"(o[15])
        : "v"(b0p), "v"(b1p), "v"(b2p), "v"(b3p)
        : "memory");
}

#define WAIT_BIND(cntstr, b)                                                   \
    asm volatile("s_waitcnt vmcnt(" cntstr ")"                                 \
        : "+v"((b)[0]), "+v"((b)[1]), "+v"((b)[2]), "+v"((b)[3]),              \
          "+v"((b)[4]), "+v"((b)[5]), "+v"((b)[6]), "+v"((b)[7]),              \
          "+v"((b)[8]), "+v"((b)[9]), "+v"((b)[10]), "+v"((b)[11]),            \
          "+v"((b)[12]), "+v"((b)[13]), "+v"((b)[14]), "+v"((b)[15])           \
        :: "memory")

__device__ __forceinline__ void st16_wt(void* p, v4i v) {      // write-through MALL
    asm volatile("global_store_dwordx4 %0, %1, off sc0 sc1" :: "v"(p), "v"(v) : "memory");
}
__device__ __forceinline__ void waitcnt0() {
    asm volatile("s_waitcnt vmcnt(0)" ::: "memory");
}

__device__ __forceinline__ void split_a(v4i A0, v4i A1, v4i& HI, v4i& LO) {
    HI.x = (int)__builtin_amdgcn_perm((unsigned)A0.y, (unsigned)A0.x, 0x07050301u);
    HI.y = (int)__builtin_amdgcn_perm((unsigned)A0.w, (unsigned)A0.z, 0x07050301u);
    HI.z = (int)__builtin_amdgcn_perm((unsigned)A1.y, (unsigned)A1.x, 0x07050301u);
    HI.w = (int)__builtin_amdgcn_perm((unsigned)A1.w, (unsigned)A1.z, 0x07050301u);
    LO.x = (int)(__builtin_amdgcn_perm((unsigned)A0.y, (unsigned)A0.x, 0x06040200u) ^ 0x80808080u);
    LO.y = (int)(__builtin_amdgcn_perm((unsigned)A0.w, (unsigned)A0.z, 0x06040200u) ^ 0x80808080u);
    LO.z = (int)(__builtin_amdgcn_perm((unsigned)A1.y, (unsigned)A1.x, 0x06040200u) ^ 0x80808080u);
    LO.w = (int)(__builtin_amdgcn_perm((unsigned)A1.w, (unsigned)A1.z, 0x06040200u) ^ 0x80808080u);
}

__device__ __forceinline__ void consume8(const v4i* hb, const char* wbase,
                                         v16i& ahh, v16i& amid)
{
#pragma unroll
    for (int s = 0; s < 8; ++s) {
        v4i HI, LO; split_a(hb[2 * s], hb[2 * s + 1], HI, LO);
        v4i BH = *(const v4i*)(wbase + s * 2048);
        v4i BL = *(const v4i*)(wbase + s * 2048 + 1024);
        ahh  = __builtin_amdgcn_mfma_i32_32x32x32_i8(HI, BH, ahh, 0, 0, 0);
        amid = __builtin_amdgcn_mfma_i32_32x32x32_i8(HI, BL, amid, 0, 0, 0);
        amid = __builtin_amdgcn_mfma_i32_32x32x32_i8(LO, BH, amid, 0, 0, 0);
    }
}

// plain cached-load kstep (x segment only; xq stays row-major)
__device__ __forceinline__ void kstep(const short* __restrict__ ap,
                                      const char* __restrict__ wl,
                                      v16i& ahh, v16i& amid)
{
    v4i A0 = *(const v4i*)ap;
    v4i A1 = *(const v4i*)(ap + 8);
    v4i HI, LO; split_a(A0, A1, HI, LO);
    v4i BH = *(const v4i*)wl;
    v4i BL = *(const v4i*)(wl + 1024);
    ahh  = __builtin_amdgcn_mfma_i32_32x32x32_i8(HI, BH, ahh, 0, 0, 0);
    amid = __builtin_amdgcn_mfma_i32_32x32x32_i8(HI, BL, amid, 0, 0, 0);
    amid = __builtin_amdgcn_mfma_i32_32x32x32_i8(LO, BH, amid, 0, 0, 0);
}

// ---------------------------------------------------------------------------
__global__ void quant_x(const float* __restrict__ x, short* __restrict__ xq, int n)
{
    int i = blockIdx.x * 256 + threadIdx.x;
    if (i < n) {
        float v = x[i] * 2048.f;
        v = fminf(fmaxf(v, -32767.f), 32767.f);
        xq[i] = (short)__float2int_rn(v);
    }
}

// prep: quantize + gate-reorder + fragment-tile weights into per-WG LDS images.
__global__ void quant_w(const float* __restrict__ wih0, const float* __restrict__ whh0,
                        const float* __restrict__ wih1, const float* __restrict__ whh1,
                        char* __restrict__ wimg)
{
    int gid = blockIdx.x * 256 + threadIdx.x;       // 256*64*64 = 1048576 threads
    if (gid >= 256 * 64 * 64) return;
    int lane = gid & 63;
    int s    = (gid >> 6) & 63;
    int wg   = gid >> 12;
    int layer = wg >> 7, nblk = wg & 127;
    int col = nblk * 32 + (lane & 31);
    int ro  = (col & 3) * 1024 + (col >> 2);        // original gate-blocked row
    int k0  = s * 32 + (lane >> 5) * 16;
    char* dst = wimg + (size_t)wg * LDS_W + s * 2048 + lane * 16;
#pragma unroll
    for (int j = 0; j < 16; ++j) {
        int k = k0 + j;
        float w = 0.f;
        if (layer == 0) {
            if (k < 256)       w = wih0[ro * 256 + k];
            else if (k < 1280) w = whh0[ro * 1024 + (k - 256)];
        } else {
            if (k < 1024)      w = wih1[ro * 1024 + k];
            else               w = whh1[ro * 1024 + (k - 1024)];
        }
        int q  = __float2int_rn(w * 524288.f);      // 2^19, |q|<=16384
        int hi = (q + 128) >> 8;
        int lo = q - (hi << 8);
        dst[j]        = (char)hi;
        dst[1024 + j] = (char)lo;
    }
}

// ---------------------------------------------------------------------------
__global__ void __launch_bounds__(128) lstm_main(
    const short* __restrict__ xq, const char* __restrict__ wimg,
    const float* __restrict__ bih0, const float* __restrict__ bhh0,
    const float* __restrict__ bih1, const float* __restrict__ bhh1,
    short* __restrict__ h0q, short* __restrict__ h2q,
    float* __restrict__ h2f, unsigned* gslots, unsigned* gbcast)
{
    extern __shared__ char smem[];
    char*  wlds = smem;
    float* gbuf = (float*)(smem + LDS_W);                       // [64][33]
    float* cbuf = (float*)(smem + LDS_W + LDS_GBUF);            // [64][9]
    float* offs = (float*)(smem + LDS_W + LDS_GBUF + LDS_CBUF); // [32]

    const int wg    = blockIdx.x;
    const int layer = wg >> 7;
    const int nblk  = wg & 127;
    const int tid   = threadIdx.x;
    const int lane  = tid & 63;
    const int RB    = tid >> 6;                   // wave = rowblock
    const float inv30 = 9.313225746154785e-10f;   // 2^-30
    const float inv33 = 1.1641532182693481e-10f;  // 2^-33

    // stage this WG's weight image into LDS (128KB)
    {
        const v4i* src = (const v4i*)(wimg + (size_t)wg * LDS_W);
        v4i* dst = (v4i*)wlds;
        for (int i = tid; i < LDS_W / 16; i += 128) dst[i] = src[i];
    }
    for (int i = tid; i < 64 * 9; i += 128) cbuf[i] = 0.f;
    __syncthreads();

    // per-col constant: 128*colsum16*inv_scale (LO'=-128 bias comp) + gate bias
    if (tid < 32) {
        const int c  = tid;
        const int ns = (layer == 0) ? 40 : 64;
        int cs_x = 0, cs_h = 0;
        for (int s = 0; s < ns; ++s) {
            int sum = 0;
#pragma unroll
            for (int half = 0; half < 2; ++half) {
                const signed char* ph = (const signed char*)(wlds + s * 2048 + (half * 32 + c) * 16);
#pragma unroll
                for (int j = 0; j < 16; ++j)
                    sum += 256 * (int)ph[j] + (int)ph[1024 + j];
            }
            if (layer == 0 && s < 8) cs_x += sum; else cs_h += sum;
        }
        const int col = nblk * 32 + c;
        const int ro  = (col & 3) * 1024 + (col >> 2);
        const float bias = (layer == 0) ? (bih0[ro] + bhh0[ro]) : (bih1[ro] + bhh1[ro]);
        float off = 128.f * (float)cs_h * inv33 + bias;
        if (layer == 0) off += 128.f * (float)cs_x * inv30;
        offs[c] = off;
    }
    __syncthreads();

    const int mrow = RB * 32 + (lane & 31);           // batch row (x segment)
    const int ksub = (lane >> 5) * 16;                // k sub-offset (x segment)
    // producer store constants: units j0..j0+7, one 16B chunk per row
    const int j0   = nblk * 8;
    const int sj   = j0 >> 5;
    const int hbj  = (j0 >> 4) & 1;
    const int inj  = (j0 & 15) * 2;

    for (int p = 0; p <= T_STEPS; ++p) {
        const bool active = (layer == 0) ? (p < T_STEPS) : (p >= 1);

        // ---- L0 x-projection BEFORE the wait (independent of phase p-1) ---
        float px[16];
        if (layer == 0 && active) {
            v16i ax = zero16(), mx = zero16();
            const short* axp = xq + ((size_t)mrow * 512 + p) * 256 + ksub;
#pragma unroll
            for (int s = 0; s < 8; ++s)
                kstep(axp + s * 32, wlds + s * 2048 + lane * 16, ax, mx);
#pragma unroll
            for (int r = 0; r < 16; ++r)
                px[r] = ((float)ax[r] * 65536.f + (float)mx[r] * 256.f) * inv30;
        }

        // ---- split-phase barrier wait (gen p), master-gather + bcast ------
        if (p > 0) {
            const unsigned pp = (unsigned)p;
            if (wg == 0) {
                const unsigned* s0 = gslots + (tid * 2) * 16;
                const unsigned* s1 = s0 + 16;
                while (__hip_atomic_load(s0, __ATOMIC_RELAXED, __HIP_MEMORY_SCOPE_AGENT) < pp)
                    __builtin_amdgcn_s_sleep(1);
                while (__hip_atomic_load(s1, __ATOMIC_RELAXED, __HIP_MEMORY_SCOPE_AGENT) < pp)
                    __builtin_amdgcn_s_sleep(1);
                __syncthreads();
                __hip_atomic_store(gbcast + (tid * 2) * 16, pp, __ATOMIC_RELAXED, __HIP_MEMORY_SCOPE_AGENT);
                __hip_atomic_store(gbcast + (tid * 2 + 1) * 16, pp, __ATOMIC_RELAXED, __HIP_MEMORY_SCOPE_AGENT);
            } else {
                if (tid == 0) {
                    while (__hip_atomic_load(gbcast + wg * 16, __ATOMIC_RELAXED, __HIP_MEMORY_SCOPE_AGENT) < pp)
                        __builtin_amdgcn_s_sleep(1);
                }
            }
            __syncthreads();
            asm volatile("" ::: "memory");
        }

        if (active) {
            // fragment-layout base for this wave/lane (bytes)
            const char* f0 = (const char*)(h0q + ((p + 1) & 1) * 65536)
                           + RB * 65536 + lane * 32;
            float gates[16];
            v16i ahh = zero16(), amid = zero16();
            v4i b0[16], b1[16];
            if (layer == 0) {
                // h segment (K=1024, weight ksteps 8..39), double-buffered
                if (p > 0) {
                    waitcnt0();   // drain stray vmcnt before counting
                    const char* W = wlds + lane * 16;
                    load_f16_nw(f0, b0);
                    load_f16_nw(f0 + 16384, b1);
                    WAIT_BIND("16", b0); consume8(b0, W + 8 * 2048, ahh, amid);
                    load_f16_nw(f0 + 32768, b0);
                    WAIT_BIND("16", b1); consume8(b1, W + 16 * 2048, ahh, amid);
                    load_f16_nw(f0 + 49152, b1);
                    WAIT_BIND("16", b0); consume8(b0, W + 24 * 2048, ahh, amid);
                    WAIT_BIND("0", b1);  consume8(b1, W + 32 * 2048, ahh, amid);
                }
#pragma unroll
                for (int r = 0; r < 16; ++r)
                    gates[r] = px[r]
                             + ((float)ahh[r] * 65536.f + (float)amid[r] * 256.f) * inv33
                             + offs[lane & 31];
            } else {
                // layer1: h0(p-1) (weight ksteps 0..31), h2(p-2) (32..63)
                const char* f2 = (const char*)(h2q + ((p + 1) & 1) * 65536)
                               + RB * 65536 + lane * 32;
                waitcnt0();
                const char* W = wlds + lane * 16;
                load_f16_nw(f0, b0);
                load_f16_nw(f0 + 16384, b1);
                WAIT_BIND("16", b0); consume8(b0, W, ahh, amid);
                load_f16_nw(f0 + 32768, b0);
                WAIT_BIND("16", b1); consume8(b1, W + 8 * 2048, ahh, amid);
                load_f16_nw(f0 + 49152, b1);
                WAIT_BIND("16", b0); consume8(b0, W + 16 * 2048, ahh, amid);
                load_f16_nw(f2, b0);
                WAIT_BIND("16", b1); consume8(b1, W + 24 * 2048, ahh, amid);
                load_f16_nw(f2 + 16384, b1);
                WAIT_BIND("16", b0); consume8(b0, W + 32 * 2048, ahh, amid);
                load_f16_nw(f2 + 32768, b0);
                WAIT_BIND("16", b1); consume8(b1, W + 40 * 2048, ahh, amid);
                load_f16_nw(f2 + 49152, b1);
                WAIT_BIND("16", b0); consume8(b0, W + 48 * 2048, ahh, amid);
                WAIT_BIND("0", b1);  consume8(b1, W + 56 * 2048, ahh, amid);
#pragma unroll
                for (int r = 0; r < 16; ++r)
                    gates[r] = ((float)ahh[r] * 65536.f + (float)amid[r] * 256.f) * inv33
                             + offs[lane & 31];
            }
            // scatter C/D frag to LDS: col=lane&31, row=(r&3)+8*(r>>2)+4*(lane>>5)
            {
                const int rbase = RB * 32 + 4 * (lane >> 5);
                const int c = lane & 31;
#pragma unroll
                for (int r = 0; r < 16; ++r) {
                    int row = rbase + (r & 3) + 8 * (r >> 2);
                    gbuf[row * 33 + c] = gates[r];
                }
            }
        }
        __syncthreads();
        if (active && tid < 64) {
            // state update: thread = row, all 8 units; ONE 16B fragment store.
            const int r = tid;
            unsigned hq[8];
            float hf[8];
#pragma unroll
            for (int u = 0; u < 8; ++u) {
                const float gi = gbuf[r * 33 + 4 * u + 0];
                const float gf = gbuf[r * 33 + 4 * u + 1];
                const float gg = gbuf[r * 33 + 4 * u + 2];
                const float go = gbuf[r * 33 + 4 * u + 3];
                const float i_ = 1.f / (1.f + __expf(-gi));
                const float f_ = 1.f / (1.f + __expf(-gf));
                const float g_ = 1.f - 2.f / (__expf(2.f * gg) + 1.f);
                const float o_ = 1.f / (1.f + __expf(-go));
                float c_ = f_ * cbuf[r * 9 + u] + i_ * g_;
                cbuf[r * 9 + u] = c_;
                const float h_ = o_ * (1.f - 2.f / (__expf(2.f * c_) + 1.f));
                hq[u] = (unsigned)(unsigned short)(short)__float2int_rn(h_ * 16384.f);
                hf[u] = h_;
            }
            v4i pk;
            pk.x = (int)(hq[0] | (hq[1] << 16));
            pk.y = (int)(hq[2] | (hq[3] << 16));
            pk.z = (int)(hq[4] | (hq[5] << 16));
            pk.w = (int)(hq[6] | (hq[7] << 16));
            char* hw = (char*)(((layer == 0) ? h0q : h2q) + (p & 1) * 65536)
                     + (r >> 5) * 65536 + sj * 2048 + ((r & 31) + 32 * hbj) * 32 + inj;
            st16_wt(hw, pk);
            if (layer == 1 && p == T_STEPS) {
#pragma unroll
                for (int u = 0; u < 8; ++u) h2f[r * 1024 + j0 + u] = hf[u];
            }
        }
        // ---- arrival (gen p+1); skip after the final phase ----------------
        if (p < T_STEPS) {
            waitcnt0();
            __syncthreads();
            if (tid == 0)
                __hip_atomic_store(gslots + wg * 16, (unsigned)(p + 1),
                                   __ATOMIC_RELAXED, __HIP_MEMORY_SCOPE_AGENT);
        }
    }
}

// ---------------------------------------------------------------------------
__global__ void final_lin(const float* __restrict__ h2f, const float* __restrict__ wlin,
                          const float* __restrict__ blin, float* __restrict__ out)
{
    const int b = blockIdx.x;
    const int l = threadIdx.x;
    float s = 0.f;
    for (int j = l; j < 1024; j += 64) s += h2f[b * 1024 + j] * wlin[j];
#pragma unroll
    for (int off = 32; off; off >>= 1) s += __shfl_down(s, off);
    if (l == 0) out[b] = s + blin[0];
}

// ---------------------------------------------------------------------------
extern "C" void kernel_launch(void* const* d_in, const int* in_sizes, int n_in,
                              void* d_out, int out_size, void* d_ws, size_t ws_size,
                              hipStream_t stream)
{
    const float* x    = (const float*)d_in[0];
    const float* wih0 = (const float*)d_in[1];
    const float* whh0 = (const float*)d_in[2];
    const float* bih0 = (const float*)d_in[3];
    const float* bhh0 = (const float*)d_in[4];
    const float* wih1 = (const float*)d_in[5];
    const float* whh1 = (const float*)d_in[6];
    const float* bih1 = (const float*)d_in[7];
    const float* bhh1 = (const float*)d_in[8];
    const float* wlin = (const float*)d_in[9];
    const float* blin = (const float*)d_in[10];

    // workspace layout (R7's)
    char* ws = (char*)d_ws;
    unsigned* gslots = (unsigned*)ws;                    // 256 x 64B
    unsigned* gbcast = (unsigned*)(ws + 16384);          // 256 x 64B
    short* h0q = (short*)(ws + 65536);                   // [2 slots][128KB] fragment
    short* h2q = (short*)(ws + 65536 + 262144);          // [2 slots][128KB] fragment
    float* h2f = (float*)(ws + 65536 + 524288);          // [64][1024] f32 = 256KB
    short* xq  = (short*)(ws + 65536 + 786432);          // 16MB
    char*  wimg = ws + 65536 + 786432 + 16777216;        // 256 * 128KB = 32MB

    // zero barrier state + h ping-pong buffers (ws re-poisoned 0xAA each call)
    hipMemsetAsync(ws, 0, 65536 + 524288, stream);

    quant_x<<<32768, 256, 0, stream>>>(x, xq, 64 * 512 * 256);
    quant_w<<<4096, 256, 0, stream>>>(wih0, whh0, wih1, whh1, wimg);

    hipFuncSetAttribute((const void*)lstm_main,
        hipFuncAttributeMaxDynamicSharedMemorySize, SMEM_BYTES);

    lstm_main<<<NWG, 128, SMEM_BYTES, stream>>>(xq, wimg, bih0, bhh0, bih1, bhh1,
                                                h0q, h2q, h2f, gslots, gbcast);
    final_lin<<<64, 64, 0, stream>>>(h2f, wlin, blin, (float*)d_out);
}

// Round 11
// 4661.552 us; speedup vs baseline: 1.5464x; 1.0348x over previous
//
#include <hip/hip_runtime.h>

// ============================================================================
// 2-layer LSTM (B=64,T=512,D=256,H=1024) + linear, fp32.
// Persistent kernel, int16 weights/acts split into two int8 planes,
// 3x i8-MFMA per K=32, fragment-native h layout (R10, proven 4.82ms).
// R11: LAG-2 diagonal. Phase p = L0 step p || L1 step p-2 (514 phases).
//   L1's h0(p-2) was posted with arrival value p-1, whose visibility the
//   PREVIOUS phase's barrier already established => L1 streams h0 (128KB,
//   ksteps 0..31) BEFORE this phase's wait, fully hidden under x-proj/poll.
//   Post-wait both layers stream exactly 128KB (L0: h0(p-1); L1: h2(p-3),
//   tight self-recurrence). Serial window halves. Barrier protocol unchanged
//   (uniform all-arrive-p; h0 ring=4, h2 ring=2 make all overwrites safe:
//   any data overwritten at phase p was last read at phase <= p-2).
//   Int accumulation reorder => bit-identical result.
// ============================================================================

#define T_STEPS 512
#define NWG 256
#define LDS_W     131072                  // [64 ksteps][2 planes][64 lanes][16B]
#define LDS_GBUF  (64 * 33 * 4)           // 8448, padded stride 33
#define LDS_CBUF  (64 * 9 * 4)            // 2304, padded stride 9
#define LDS_OFFS  (32 * 4)
#define SMEM_BYTES (LDS_W + LDS_GBUF + LDS_CBUF + LDS_OFFS)   // 141952

typedef int v2i  __attribute__((ext_vector_type(2)));
typedef int v4i  __attribute__((ext_vector_type(4)));
typedef int v16i __attribute__((ext_vector_type(16)));

__device__ __forceinline__ v16i zero16() {
    v16i z;
#pragma unroll
    for (int i = 0; i < 16; ++i) z[i] = 0;
    return z;
}

// One 8-kstep batch from fragment layout: 16 lane-contiguous dwordx4
// (sc0 sc1, MALL-direct), NO trailing wait. kstep s at +s*2048, A0/A1 +0/+16.
__device__ __forceinline__ void load_f16_nw(const char* b0p, v4i* o) {
    const char* b1p = b0p + 4096;
    const char* b2p = b0p + 8192;
    const char* b3p = b0p + 12288;
    asm volatile(
        "global_load_dwordx4 %0, %16, off sc0 sc1\n\t"
        "global_load_dwordx4 %1, %16, off offset:16 sc0 sc1\n\t"
        "global_load_dwordx4 %2, %16, off offset:2048 sc0 sc1\n\t"
        "global_load_dwordx4 %3, %16, off offset:2064 sc0 sc1\n\t"
        "global_load_dwordx4 %4, %17, off sc0 sc1\n\t"
        "global_load_dwordx4 %5, %17, off offset:16 sc0 sc1\n\t"
        "global_load_dwordx4 %6, %17, off offset:2048 sc0 sc1\n\t"
        "global_load_dwordx4 %7, %17, off offset:2064 sc0 sc1\n\t"
        "global_load_dwordx4 %8, %18, off sc0 sc1\n\t"
        "global_load_dwordx4 %9, %18, off offset:16 sc0 sc1\n\t"
        "global_load_dwordx4 %10, %18, off offset:2048 sc0 sc1\n\t"
        "global_load_dwordx4 %11, %18, off offset:2064 sc0 sc1\n\t"
        "global_load_dwordx4 %12, %19, off sc0 sc1\n\t"
        "global_load_dwordx4 %13, %19, off offset:16 sc0 sc1\n\t"
        "global_load_dwordx4 %14, %19, off offset:2048 sc0 sc1\n\t"
        "global_load_dwordx4 %15, %19, off offset:2064 sc0 sc1"
        : "=&v"(o[0]), "=&v"(o[1]), "=&v"(o[2]), "=&v"(o[3]),
          "=&v"(o[4]), "=&v"(o[5]), "=&v"(o[6]), "=&v"(o[7]),
          "=&v"(o[8]), "=&v"(o[9]), "=&v"(o[10]), "=&v"(o[11]),
          "=&v"(o[12]), "=&v"(o[13]), "=&v"(o[14]), "=&v"(o[15])
        : "v"(b0p), "v"(b1p), "v"(b2p), "v"(b3p)
        : "memory");
}

#define WAIT_BIND(cntstr, b)                                                   \
    asm volatile("s_waitcnt vmcnt(" cntstr ")"                                 \
        : "+v"((b)[0]), "+v"((b)[1]), "+v"((b)[2]), "+v"((b)[3]),              \
          "+v"((b)[4]), "+v"((b)[5]), "+v"((b)[6]), "+v"((b)[7]),              \
          "+v"((b)[8]), "+v"((b)[9]), "+v"((b)[10]), "+v"((b)[11]),            \
          "+v"((b)[12]), "+v"((b)[13]), "+v"((b)[14]), "+v"((b)[15])           \
        :: "memory")

__device__ __forceinline__ void st16_wt(void* p, v4i v) {      // write-through MALL
    asm volatile("global_store_dwordx4 %0, %1, off sc0 sc1" :: "v"(p), "v"(v) : "memory");
}
__device__ __forceinline__ void waitcnt0() {
    asm volatile("s_waitcnt vmcnt(0)" ::: "memory");
}

__device__ __forceinline__ void split_a(v4i A0, v4i A1, v4i& HI, v4i& LO) {
    HI.x = (int)__builtin_amdgcn_perm((unsigned)A0.y, (unsigned)A0.x, 0x07050301u);
    HI.y = (int)__builtin_amdgcn_perm((unsigned)A0.w, (unsigned)A0.z, 0x07050301u);
    HI.z = (int)__builtin_amdgcn_perm((unsigned)A1.y, (unsigned)A1.x, 0x07050301u);
    HI.w = (int)__builtin_amdgcn_perm((unsigned)A1.w, (unsigned)A1.z, 0x07050301u);
    LO.x = (int)(__builtin_amdgcn_perm((unsigned)A0.y, (unsigned)A0.x, 0x06040200u) ^ 0x80808080u);
    LO.y = (int)(__builtin_amdgcn_perm((unsigned)A0.w, (unsigned)A0.z, 0x06040200u) ^ 0x80808080u);
    LO.z = (int)(__builtin_amdgcn_perm((unsigned)A1.y, (unsigned)A1.x, 0x06040200u) ^ 0x80808080u);
    LO.w = (int)(__builtin_amdgcn_perm((unsigned)A1.w, (unsigned)A1.z, 0x06040200u) ^ 0x80808080u);
}

__device__ __forceinline__ void consume8(const v4i* hb, const char* wbase,
                                         v16i& ahh, v16i& amid)
{
#pragma unroll
    for (int s = 0; s < 8; ++s) {
        v4i HI, LO; split_a(hb[2 * s], hb[2 * s + 1], HI, LO);
        v4i BH = *(const v4i*)(wbase + s * 2048);
        v4i BL = *(const v4i*)(wbase + s * 2048 + 1024);
        ahh  = __builtin_amdgcn_mfma_i32_32x32x32_i8(HI, BH, ahh, 0, 0, 0);
        amid = __builtin_amdgcn_mfma_i32_32x32x32_i8(HI, BL, amid, 0, 0, 0);
        amid = __builtin_amdgcn_mfma_i32_32x32x32_i8(LO, BH, amid, 0, 0, 0);
    }
}

// plain cached-load kstep (x segment only; xq stays row-major)
__device__ __forceinline__ void kstep(const short* __restrict__ ap,
                                      const char* __restrict__ wl,
                                      v16i& ahh, v16i& amid)
{
    v4i A0 = *(const v4i*)ap;
    v4i A1 = *(const v4i*)(ap + 8);
    v4i HI, LO; split_a(A0, A1, HI, LO);
    v4i BH = *(const v4i*)wl;
    v4i BL = *(const v4i*)(wl + 1024);
    ahh  = __builtin_amdgcn_mfma_i32_32x32x32_i8(HI, BH, ahh, 0, 0, 0);
    amid = __builtin_amdgcn_mfma_i32_32x32x32_i8(HI, BL, amid, 0, 0, 0);
    amid = __builtin_amdgcn_mfma_i32_32x32x32_i8(LO, BH, amid, 0, 0, 0);
}

// ---------------------------------------------------------------------------
__global__ void quant_x(const float* __restrict__ x, short* __restrict__ xq, int n)
{
    int i = blockIdx.x * 256 + threadIdx.x;
    if (i < n) {
        float v = x[i] * 2048.f;
        v = fminf(fmaxf(v, -32767.f), 32767.f);
        xq[i] = (short)__float2int_rn(v);
    }
}

// prep: quantize + gate-reorder + fragment-tile weights into per-WG LDS images.
__global__ void quant_w(const float* __restrict__ wih0, const float* __restrict__ whh0,
                        const float* __restrict__ wih1, const float* __restrict__ whh1,
                        char* __restrict__ wimg)
{
    int gid = blockIdx.x * 256 + threadIdx.x;       // 256*64*64 = 1048576 threads
    if (gid >= 256 * 64 * 64) return;
    int lane = gid & 63;
    int s    = (gid >> 6) & 63;
    int wg   = gid >> 12;
    int layer = wg >> 7, nblk = wg & 127;
    int col = nblk * 32 + (lane & 31);
    int ro  = (col & 3) * 1024 + (col >> 2);        // original gate-blocked row
    int k0  = s * 32 + (lane >> 5) * 16;
    char* dst = wimg + (size_t)wg * LDS_W + s * 2048 + lane * 16;
#pragma unroll
    for (int j = 0; j < 16; ++j) {
        int k = k0 + j;
        float w = 0.f;
        if (layer == 0) {
            if (k < 256)       w = wih0[ro * 256 + k];
            else if (k < 1280) w = whh0[ro * 1024 + (k - 256)];
        } else {
            if (k < 1024)      w = wih1[ro * 1024 + k];
            else               w = whh1[ro * 1024 + (k - 1024)];
        }
        int q  = __float2int_rn(w * 524288.f);      // 2^19, |q|<=16384
        int hi = (q + 128) >> 8;
        int lo = q - (hi << 8);
        dst[j]        = (char)hi;
        dst[1024 + j] = (char)lo;
    }
}

// ---------------------------------------------------------------------------
__global__ void __launch_bounds__(128) lstm_main(
    const short* __restrict__ xq, const char* __restrict__ wimg,
    const float* __restrict__ bih0, const float* __restrict__ bhh0,
    const float* __restrict__ bih1, const float* __restrict__ bhh1,
    short* __restrict__ h0q, short* __restrict__ h2q,
    float* __restrict__ h2f, unsigned* gslots, unsigned* gbcast)
{
    extern __shared__ char smem[];
    char*  wlds = smem;
    float* gbuf = (float*)(smem + LDS_W);                       // [64][33]
    float* cbuf = (float*)(smem + LDS_W + LDS_GBUF);            // [64][9]
    float* offs = (float*)(smem + LDS_W + LDS_GBUF + LDS_CBUF); // [32]

    const int wg    = blockIdx.x;
    const int layer = wg >> 7;
    const int nblk  = wg & 127;
    const int tid   = threadIdx.x;
    const int lane  = tid & 63;
    const int RB    = tid >> 6;                   // wave = rowblock
    const float inv30 = 9.313225746154785e-10f;   // 2^-30
    const float inv33 = 1.1641532182693481e-10f;  // 2^-33

    // stage this WG's weight image into LDS (128KB)
    {
        const v4i* src = (const v4i*)(wimg + (size_t)wg * LDS_W);
        v4i* dst = (v4i*)wlds;
        for (int i = tid; i < LDS_W / 16; i += 128) dst[i] = src[i];
    }
    for (int i = tid; i < 64 * 9; i += 128) cbuf[i] = 0.f;
    __syncthreads();

    // per-col constant: 128*colsum16*inv_scale (LO'=-128 bias comp) + gate bias
    if (tid < 32) {
        const int c  = tid;
        const int ns = (layer == 0) ? 40 : 64;
        int cs_x = 0, cs_h = 0;
        for (int s = 0; s < ns; ++s) {
            int sum = 0;
#pragma unroll
            for (int half = 0; half < 2; ++half) {
                const signed char* ph = (const signed char*)(wlds + s * 2048 + (half * 32 + c) * 16);
#pragma unroll
                for (int j = 0; j < 16; ++j)
                    sum += 256 * (int)ph[j] + (int)ph[1024 + j];
            }
            if (layer == 0 && s < 8) cs_x += sum; else cs_h += sum;
        }
        const int col = nblk * 32 + c;
        const int ro  = (col & 3) * 1024 + (col >> 2);
        const float bias = (layer == 0) ? (bih0[ro] + bhh0[ro]) : (bih1[ro] + bhh1[ro]);
        float off = 128.f * (float)cs_h * inv33 + bias;
        if (layer == 0) off += 128.f * (float)cs_x * inv30;
        offs[c] = off;
    }
    __syncthreads();

    const int mrow = RB * 32 + (lane & 31);           // batch row (x segment)
    const int ksub = (lane >> 5) * 16;                // k sub-offset (x segment)
    // producer store constants: units j0..j0+7, one 16B chunk per row
    const int j0   = nblk * 8;
    const int sj   = j0 >> 5;
    const int hbj  = (j0 >> 4) & 1;
    const int inj  = (j0 & 15) * 2;

    // phase p: L0 computes step p (p<T); L1 computes step p-2 (p>=2).
    for (int p = 0; p <= T_STEPS + 1; ++p) {
        const bool actL0 = (layer == 0) && (p < T_STEPS);
        const bool actL1 = (layer == 1) && (p >= 2);
        const bool active = actL0 || actL1;

        float px[16];
        v16i ahh = zero16(), amid = zero16();

        // ---- pre-wait work (independent of this phase's barrier) ----------
        if (actL0) {
            // x-projection for step p
            v16i ax = zero16(), mx = zero16();
            const short* axp = xq + ((size_t)mrow * 512 + p) * 256 + ksub;
#pragma unroll
            for (int s = 0; s < 8; ++s)
                kstep(axp + s * 32, wlds + s * 2048 + lane * 16, ax, mx);
#pragma unroll
            for (int r = 0; r < 16; ++r)
                px[r] = ((float)ax[r] * 65536.f + (float)mx[r] * 256.f) * inv30;
        } else if (actL1) {
            // hoisted h0(p-2) stream (visibility established by PREVIOUS
            // phase's barrier: h0(p-2) posted with arrival value p-1).
            const char* f0 = (const char*)h0q + ((p - 2) & 3) * 131072
                           + RB * 65536 + lane * 32;
            v4i b0[16], b1[16];
            waitcnt0();
            const char* W = wlds + lane * 16;
            load_f16_nw(f0, b0);
            load_f16_nw(f0 + 16384, b1);
            WAIT_BIND("16", b0); consume8(b0, W, ahh, amid);
            load_f16_nw(f0 + 32768, b0);
            WAIT_BIND("16", b1); consume8(b1, W + 8 * 2048, ahh, amid);
            load_f16_nw(f0 + 49152, b1);
            WAIT_BIND("16", b0); consume8(b0, W + 16 * 2048, ahh, amid);
            WAIT_BIND("0", b1);  consume8(b1, W + 24 * 2048, ahh, amid);
        }

        // ---- split-phase barrier wait (gen p), master-gather + bcast ------
        if (p > 0) {
            const unsigned pp = (unsigned)p;
            if (wg == 0) {
                const unsigned* s0 = gslots + (tid * 2) * 16;
                const unsigned* s1 = s0 + 16;
                while (__hip_atomic_load(s0, __ATOMIC_RELAXED, __HIP_MEMORY_SCOPE_AGENT) < pp)
                    __builtin_amdgcn_s_sleep(1);
                while (__hip_atomic_load(s1, __ATOMIC_RELAXED, __HIP_MEMORY_SCOPE_AGENT) < pp)
                    __builtin_amdgcn_s_sleep(1);
                __syncthreads();
                __hip_atomic_store(gbcast + (tid * 2) * 16, pp, __ATOMIC_RELAXED, __HIP_MEMORY_SCOPE_AGENT);
                __hip_atomic_store(gbcast + (tid * 2 + 1) * 16, pp, __ATOMIC_RELAXED, __HIP_MEMORY_SCOPE_AGENT);
            } else {
                if (tid == 0) {
                    while (__hip_atomic_load(gbcast + wg * 16, __ATOMIC_RELAXED, __HIP_MEMORY_SCOPE_AGENT) < pp)
                        __builtin_amdgcn_s_sleep(1);
                }
            }
            __syncthreads();
            asm volatile("" ::: "memory");
        }

        if (active) {
            float gates[16];
            v4i b0[16], b1[16];
            if (layer == 0) {
                // h0(p-1) stream (weight ksteps 8..39); h(-1)=0 -> skip at p=0
                if (p > 0) {
                    const char* f0 = (const char*)h0q + ((p - 1) & 3) * 131072
                                   + RB * 65536 + lane * 32;
                    waitcnt0();
                    const char* W = wlds + lane * 16;
                    load_f16_nw(f0, b0);
                    load_f16_nw(f0 + 16384, b1);
                    WAIT_BIND("16", b0); consume8(b0, W + 8 * 2048, ahh, amid);
                    load_f16_nw(f0 + 32768, b0);
                    WAIT_BIND("16", b1); consume8(b1, W + 16 * 2048, ahh, amid);
                    load_f16_nw(f0 + 49152, b1);
                    WAIT_BIND("16", b0); consume8(b0, W + 24 * 2048, ahh, amid);
                    WAIT_BIND("0", b1);  consume8(b1, W + 32 * 2048, ahh, amid);
                }
#pragma unroll
                for (int r = 0; r < 16; ++r)
                    gates[r] = px[r]
                             + ((float)ahh[r] * 65536.f + (float)amid[r] * 256.f) * inv33
                             + offs[lane & 31];
            } else {
                // h2(p-3) stream (weight ksteps 32..63); h2(-1)=0 -> skip p=2
                if (p > 2) {
                    const char* f2 = (const char*)h2q + ((p - 3) & 1) * 131072
                                   + RB * 65536 + lane * 32;
                    waitcnt0();
                    const char* W = wlds + lane * 16;
                    load_f16_nw(f2, b0);
                    load_f16_nw(f2 + 16384, b1);
                    WAIT_BIND("16", b0); consume8(b0, W + 32 * 2048, ahh, amid);
                    load_f16_nw(f2 + 32768, b0);
                    WAIT_BIND("16", b1); consume8(b1, W + 40 * 2048, ahh, amid);
                    load_f16_nw(f2 + 49152, b1);
                    WAIT_BIND("16", b0); consume8(b0, W + 48 * 2048, ahh, amid);
                    WAIT_BIND("0", b1);  consume8(b1, W + 56 * 2048, ahh, amid);
                }
#pragma unroll
                for (int r = 0; r < 16; ++r)
                    gates[r] = ((float)ahh[r] * 65536.f + (float)amid[r] * 256.f) * inv33
                             + offs[lane & 31];
            }
            // scatter C/D frag to LDS: col=lane&31, row=(r&3)+8*(r>>2)+4*(lane>>5)
            {
                const int rbase = RB * 32 + 4 * (lane >> 5);
                const int c = lane & 31;
#pragma unroll
                for (int r = 0; r < 16; ++r) {
                    int row = rbase + (r & 3) + 8 * (r >> 2);
                    gbuf[row * 33 + c] = gates[r];
                }
            }
        }
        __syncthreads();
        if (active && tid < 64) {
            // state update: thread = row, all 8 units; ONE 16B fragment store.
            const int r = tid;
            unsigned hq[8];
            float hf[8];
#pragma unroll
            for (int u = 0; u < 8; ++u) {
                const float gi = gbuf[r * 33 + 4 * u + 0];
                const float gf = gbuf[r * 33 + 4 * u + 1];
                const float gg = gbuf[r * 33 + 4 * u + 2];
                const float go = gbuf[r * 33 + 4 * u + 3];
                const float i_ = 1.f / (1.f + __expf(-gi));
                const float f_ = 1.f / (1.f + __expf(-gf));
                const float g_ = 1.f - 2.f / (__expf(2.f * gg) + 1.f);
                const float o_ = 1.f / (1.f + __expf(-go));
                float c_ = f_ * cbuf[r * 9 + u] + i_ * g_;
                cbuf[r * 9 + u] = c_;
                const float h_ = o_ * (1.f - 2.f / (__expf(2.f * c_) + 1.f));
                hq[u] = (unsigned)(unsigned short)(short)__float2int_rn(h_ * 16384.f);
                hf[u] = h_;
            }
            v4i pk;
            pk.x = (int)(hq[0] | (hq[1] << 16));
            pk.y = (int)(hq[2] | (hq[3] << 16));
            pk.z = (int)(hq[4] | (hq[5] << 16));
            pk.w = (int)(hq[6] | (hq[7] << 16));
            // L0 writes h0(p) slot p&3; L1 writes h2(p-2) slot (p-2)&1
            char* hw = (layer == 0)
                     ? (char*)h0q + (p & 3) * 131072
                     : (char*)h2q + ((p - 2) & 1) * 131072;
            hw += (r >> 5) * 65536 + sj * 2048 + ((r & 31) + 32 * hbj) * 32 + inj;
            st16_wt(hw, pk);
            if (layer == 1 && p == T_STEPS + 1) {
#pragma unroll
                for (int u = 0; u < 8; ++u) h2f[r * 1024 + j0 + u] = hf[u];
            }
        }
        // ---- arrival (gen p+1); skip after the final phase ----------------
        if (p < T_STEPS + 1) {
            waitcnt0();
            __syncthreads();
            if (tid == 0)
                __hip_atomic_store(gslots + wg * 16, (unsigned)(p + 1),
                                   __ATOMIC_RELAXED, __HIP_MEMORY_SCOPE_AGENT);
        }
    }
}

// ---------------------------------------------------------------------------
__global__ void final_lin(const float* __restrict__ h2f, const float* __restrict__ wlin,
                          const float* __restrict__ blin, float* __restrict__ out)
{
    const int b = blockIdx.x;
    const int l = threadIdx.x;
    float s = 0.f;
    for (int j = l; j < 1024; j += 64) s += h2f[b * 1024 + j] * wlin[j];
#pragma unroll
    for (int off = 32; off; off >>= 1) s += __shfl_down(s, off);
    if (l == 0) out[b] = s + blin[0];
}

// ---------------------------------------------------------------------------
extern "C" void kernel_launch(void* const* d_in, const int* in_sizes, int n_in,
                              void* d_out, int out_size, void* d_ws, size_t ws_size,
                              hipStream_t stream)
{
    const float* x    = (const float*)d_in[0];
    const float* wih0 = (const float*)d_in[1];
    const float* whh0 = (const float*)d_in[2];
    const float* bih0 = (const float*)d_in[3];
    const float* bhh0 = (const float*)d_in[4];
    const float* wih1 = (const float*)d_in[5];
    const float* whh1 = (const float*)d_in[6];
    const float* bih1 = (const float*)d_in[7];
    const float* bhh1 = (const float*)d_in[8];
    const float* wlin = (const float*)d_in[9];
    const float* blin = (const float*)d_in[10];

    // workspace layout
    char* ws = (char*)d_ws;
    unsigned* gslots = (unsigned*)ws;                    // 256 x 64B
    unsigned* gbcast = (unsigned*)(ws + 16384);          // 256 x 64B
    short* h0q = (short*)(ws + 65536);                   // [4 slots][128KB] fragment ring
    short* h2q = (short*)(ws + 65536 + 524288);          // [2 slots][128KB] fragment ring
    float* h2f = (float*)(ws + 65536 + 786432);          // [64][1024] f32 = 256KB
    short* xq  = (short*)(ws + 65536 + 1048576);         // 16MB
    char*  wimg = ws + 65536 + 1048576 + 16777216;       // 256 * 128KB = 32MB

    // zero barrier state (h rings are written before any read)
    hipMemsetAsync(ws, 0, 65536, stream);

    quant_x<<<32768, 256, 0, stream>>>(x, xq, 64 * 512 * 256);
    quant_w<<<4096, 256, 0, stream>>>(wih0, whh0, wih1, whh1, wimg);

    hipFuncSetAttribute((const void*)lstm_main,
        hipFuncAttributeMaxDynamicSharedMemorySize, SMEM_BYTES);

    lstm_main<<<NWG, 128, SMEM_BYTES, stream>>>(xq, wimg, bih0, bhh0, bih1, bhh1,
                                                h0q, h2q, h2f, gslots, gbcast);
    final_lin<<<64, 64, 0, stream>>>(h2f, wlin, blin, (float*)d_out);
}

// Round 12
// 4305.353 us; speedup vs baseline: 1.6743x; 1.0827x over previous
//
#include <hip/hip_runtime.h>

// ============================================================================
// 2-layer LSTM (B=64,T=512,D=256,H=1024) + linear, fp32.
// Persistent kernel, int16 weights/acts split into two int8 planes,
// 3x i8-MFMA per K=32, fragment-native h layout (R10), lag-2 diagonal (R11,
// proven 4.66ms: phase p = L0 step p || L1 step p-2).
// R12: ONE-HOP SUBSET POLLING replaces the two-hop master-gather barrier.
//   Slot stores are releases (waitcnt0 precedes them), so consumers need only
//   poll their PRODUCERS' slots:
//    - L0 @p: L0 slots >= p (RAW h0(p-1)) + lag-guard L1 >= p-5 (WAR, h0
//      ring=8; normally pre-satisfied).
//    - L1 @p: pre-guard L0 >= p-1 (for hoisted h0(p-2) stream, pre-satisfied),
//      then L1 slots >= p (RAW h2(p-3); WAR implied, h2 ring=4).
//   One poll observation (~0.5us) instead of gather+bcast (~2-2.5us), and the
//   two chains decouple. Poll = 8-16 coalesced lines/WG at s_sleep(3) — ~1/6
//   of R9's traffic (R9 proved the store/poll primitive correct; its only
//   failure was congestion). Data path byte-identical to R11.
// ============================================================================

#define T_STEPS 512
#define NWG 256
#define LDS_W     131072                  // [64 ksteps][2 planes][64 lanes][16B]
#define LDS_GBUF  (64 * 33 * 4)           // 8448, padded stride 33
#define LDS_CBUF  (64 * 9 * 4)            // 2304, padded stride 9
#define LDS_OFFS  (32 * 4)
#define SMEM_BYTES (LDS_W + LDS_GBUF + LDS_CBUF + LDS_OFFS)   // 141952

typedef int v2i  __attribute__((ext_vector_type(2)));
typedef int v4i  __attribute__((ext_vector_type(4)));
typedef int v16i __attribute__((ext_vector_type(16)));

__device__ __forceinline__ v16i zero16() {
    v16i z;
#pragma unroll
    for (int i = 0; i < 16; ++i) z[i] = 0;
    return z;
}

// One 8-kstep batch from fragment layout: 16 lane-contiguous dwordx4
// (sc0 sc1, MALL-direct), NO trailing wait. kstep s at +s*2048, A0/A1 +0/+16.
__device__ __forceinline__ void load_f16_nw(const char* b0p, v4i* o) {
    const char* b1p = b0p + 4096;
    const char* b2p = b0p + 8192;
    const char* b3p = b0p + 12288;
    asm volatile(
        "global_load_dwordx4 %0, %16, off sc0 sc1\n\t"
        "global_load_dwordx4 %1, %16, off offset:16 sc0 sc1\n\t"
        "global_load_dwordx4 %2, %16, off offset:2048 sc0 sc1\n\t"
        "global_load_dwordx4 %3, %16, off offset:2064 sc0 sc1\n\t"
        "global_load_dwordx4 %4, %17, off sc0 sc1\n\t"
        "global_load_dwordx4 %5, %17, off offset:16 sc0 sc1\n\t"
        "global_load_dwordx4 %6, %17, off offset:2048 sc0 sc1\n\t"
        "global_load_dwordx4 %7, %17, off offset:2064 sc0 sc1\n\t"
        "global_load_dwordx4 %8, %18, off sc0 sc1\n\t"
        "global_load_dwordx4 %9, %18, off offset:16 sc0 sc1\n\t"
        "global_load_dwordx4 %10, %18, off offset:2048 sc0 sc1\n\t"
        "global_load_dwordx4 %11, %18, off offset:2064 sc0 sc1\n\t"
        "global_load_dwordx4 %12, %19, off sc0 sc1\n\t"
        "global_load_dwordx4 %13, %19, off offset:16 sc0 sc1\n\t"
        "global_load_dwordx4 %14, %19, off offset:2048 sc0 sc1\n\t"
        "global_load_dwordx4 %15, %19, off offset:2064 sc0 sc1"
        : "=&v"(o[0]), "=&v"(o[1]), "=&v"(o[2]), "=&v"(o[3]),
          "=&v"(o[4]), "=&v"(o[5]), "=&v"(o[6]), "=&v"(o[7]),
          "=&v"(o[8]), "=&v"(o[9]), "=&v"(o[10]), "=&v"(o[11]),
          "=&v"(o[12]), "=&v"(o[13]), "=&v"(o[14]), "=&v"(o[15])
        : "v"(b0p), "v"(b1p), "v"(b2p), "v"(b3p)
        : "memory");
}

#define WAIT_BIND(cntstr, b)                                                   \
    asm volatile("s_waitcnt vmcnt(" cntstr ")"                                 \
        : "+v"((b)[0]), "+v"((b)[1]), "+v"((b)[2]), "+v"((b)[3]),              \
          "+v"((b)[4]), "+v"((b)[5]), "+v"((b)[6]), "+v"((b)[7]),              \
          "+v"((b)[8]), "+v"((b)[9]), "+v"((b)[10]), "+v"((b)[11]),            \
          "+v"((b)[12]), "+v"((b)[13]), "+v"((b)[14]), "+v"((b)[15])           \
        :: "memory")

__device__ __forceinline__ void st16_wt(void* p, v4i v) {      // write-through MALL
    asm volatile("global_store_dwordx4 %0, %1, off sc0 sc1" :: "v"(p), "v"(v) : "memory");
}
__device__ __forceinline__ void store_slot(unsigned* p, unsigned v) {
    asm volatile("global_store_dword %0, %1, off sc0 sc1" :: "v"(p), "v"(v) : "memory");
}
__device__ __forceinline__ v4i ld4_mall(const unsigned* p) {
    v4i r;
    asm volatile("global_load_dwordx4 %0, %1, off sc0 sc1\n\ts_waitcnt vmcnt(0)"
                 : "=v"(r) : "v"(p) : "memory");
    return r;
}
__device__ __forceinline__ void waitcnt0() {
    asm volatile("s_waitcnt vmcnt(0)" ::: "memory");
}

__device__ __forceinline__ void split_a(v4i A0, v4i A1, v4i& HI, v4i& LO) {
    HI.x = (int)__builtin_amdgcn_perm((unsigned)A0.y, (unsigned)A0.x, 0x07050301u);
    HI.y = (int)__builtin_amdgcn_perm((unsigned)A0.w, (unsigned)A0.z, 0x07050301u);
    HI.z = (int)__builtin_amdgcn_perm((unsigned)A1.y, (unsigned)A1.x, 0x07050301u);
    HI.w = (int)__builtin_amdgcn_perm((unsigned)A1.w, (unsigned)A1.z, 0x07050301u);
    LO.x = (int)(__builtin_amdgcn_perm((unsigned)A0.y, (unsigned)A0.x, 0x06040200u) ^ 0x80808080u);
    LO.y = (int)(__builtin_amdgcn_perm((unsigned)A0.w, (unsigned)A0.z, 0x06040200u) ^ 0x80808080u);
    LO.z = (int)(__builtin_amdgcn_perm((unsigned)A1.y, (unsigned)A1.x, 0x06040200u) ^ 0x80808080u);
    LO.w = (int)(__builtin_amdgcn_perm((unsigned)A1.w, (unsigned)A1.z, 0x06040200u) ^ 0x80808080u);
}

__device__ __forceinline__ void consume8(const v4i* hb, const char* wbase,
                                         v16i& ahh, v16i& amid)
{
#pragma unroll
    for (int s = 0; s < 8; ++s) {
        v4i HI, LO; split_a(hb[2 * s], hb[2 * s + 1], HI, LO);
        v4i BH = *(const v4i*)(wbase + s * 2048);
        v4i BL = *(const v4i*)(wbase + s * 2048 + 1024);
        ahh  = __builtin_amdgcn_mfma_i32_32x32x32_i8(HI, BH, ahh, 0, 0, 0);
        amid = __builtin_amdgcn_mfma_i32_32x32x32_i8(HI, BL, amid, 0, 0, 0);
        amid = __builtin_amdgcn_mfma_i32_32x32x32_i8(LO, BH, amid, 0, 0, 0);
    }
}

// plain cached-load kstep (x segment only; xq stays row-major)
__device__ __forceinline__ void kstep(const short* __restrict__ ap,
                                      const char* __restrict__ wl,
                                      v16i& ahh, v16i& amid)
{
    v4i A0 = *(const v4i*)ap;
    v4i A1 = *(const v4i*)(ap + 8);
    v4i HI, LO; split_a(A0, A1, HI, LO);
    v4i BH = *(const v4i*)wl;
    v4i BL = *(const v4i*)(wl + 1024);
    ahh  = __builtin_amdgcn_mfma_i32_32x32x32_i8(HI, BH, ahh, 0, 0, 0);
    amid = __builtin_amdgcn_mfma_i32_32x32x32_i8(HI, BL, amid, 0, 0, 0);
    amid = __builtin_amdgcn_mfma_i32_32x32x32_i8(LO, BH, amid, 0, 0, 0);
}

// ---------------------------------------------------------------------------
__global__ void quant_x(const float* __restrict__ x, short* __restrict__ xq, int n)
{
    int i = blockIdx.x * 256 + threadIdx.x;
    if (i < n) {
        float v = x[i] * 2048.f;
        v = fminf(fmaxf(v, -32767.f), 32767.f);
        xq[i] = (short)__float2int_rn(v);
    }
}

// prep: quantize + gate-reorder + fragment-tile weights into per-WG LDS images.
__global__ void quant_w(const float* __restrict__ wih0, const float* __restrict__ whh0,
                        const float* __restrict__ wih1, const float* __restrict__ whh1,
                        char* __restrict__ wimg)
{
    int gid = blockIdx.x * 256 + threadIdx.x;       // 256*64*64 = 1048576 threads
    if (gid >= 256 * 64 * 64) return;
    int lane = gid & 63;
    int s    = (gid >> 6) & 63;
    int wg   = gid >> 12;
    int layer = wg >> 7, nblk = wg & 127;
    int col = nblk * 32 + (lane & 31);
    int ro  = (col & 3) * 1024 + (col >> 2);        // original gate-blocked row
    int k0  = s * 32 + (lane >> 5) * 16;
    char* dst = wimg + (size_t)wg * LDS_W + s * 2048 + lane * 16;
#pragma unroll
    for (int j = 0; j < 16; ++j) {
        int k = k0 + j;
        float w = 0.f;
        if (layer == 0) {
            if (k < 256)       w = wih0[ro * 256 + k];
            else if (k < 1280) w = whh0[ro * 1024 + (k - 256)];
        } else {
            if (k < 1024)      w = wih1[ro * 1024 + k];
            else               w = whh1[ro * 1024 + (k - 1024)];
        }
        int q  = __float2int_rn(w * 524288.f);      // 2^19, |q|<=16384
        int hi = (q + 128) >> 8;
        int lo = q - (hi << 8);
        dst[j]        = (char)hi;
        dst[1024 + j] = (char)lo;
    }
}

// ---------------------------------------------------------------------------
__global__ void __launch_bounds__(128) lstm_main(
    const short* __restrict__ xq, const char* __restrict__ wimg,
    const float* __restrict__ bih0, const float* __restrict__ bhh0,
    const float* __restrict__ bih1, const float* __restrict__ bhh1,
    short* __restrict__ h0q, short* __restrict__ h2q,
    float* __restrict__ h2f, unsigned* gslots)
{
    extern __shared__ char smem[];
    char*  wlds = smem;
    float* gbuf = (float*)(smem + LDS_W);                       // [64][33]
    float* cbuf = (float*)(smem + LDS_W + LDS_GBUF);            // [64][9]
    float* offs = (float*)(smem + LDS_W + LDS_GBUF + LDS_CBUF); // [32]

    const int wg    = blockIdx.x;
    const int layer = wg >> 7;
    const int nblk  = wg & 127;
    const int tid   = threadIdx.x;
    const int lane  = tid & 63;
    const int RB    = tid >> 6;                   // wave = rowblock
    const float inv30 = 9.313225746154785e-10f;   // 2^-30
    const float inv33 = 1.1641532182693481e-10f;  // 2^-33

    // stage this WG's weight image into LDS (128KB)
    {
        const v4i* src = (const v4i*)(wimg + (size_t)wg * LDS_W);
        v4i* dst = (v4i*)wlds;
        for (int i = tid; i < LDS_W / 16; i += 128) dst[i] = src[i];
    }
    for (int i = tid; i < 64 * 9; i += 128) cbuf[i] = 0.f;
    __syncthreads();

    // per-col constant: 128*colsum16*inv_scale (LO'=-128 bias comp) + gate bias
    if (tid < 32) {
        const int c  = tid;
        const int ns = (layer == 0) ? 40 : 64;
        int cs_x = 0, cs_h = 0;
        for (int s = 0; s < ns; ++s) {
            int sum = 0;
#pragma unroll
            for (int half = 0; half < 2; ++half) {
                const signed char* ph = (const signed char*)(wlds + s * 2048 + (half * 32 + c) * 16);
#pragma unroll
                for (int j = 0; j < 16; ++j)
                    sum += 256 * (int)ph[j] + (int)ph[1024 + j];
            }
            if (layer == 0 && s < 8) cs_x += sum; else cs_h += sum;
        }
        const int col = nblk * 32 + c;
        const int ro  = (col & 3) * 1024 + (col >> 2);
        const float bias = (layer == 0) ? (bih0[ro] + bhh0[ro]) : (bih1[ro] + bhh1[ro]);
        float off = 128.f * (float)cs_h * inv33 + bias;
        if (layer == 0) off += 128.f * (float)cs_x * inv30;
        offs[c] = off;
    }
    __syncthreads();

    const int mrow = RB * 32 + (lane & 31);           // batch row (x segment)
    const int ksub = (lane >> 5) * 16;                // k sub-offset (x segment)
    // producer store constants: units j0..j0+7, one 16B chunk per row
    const int j0   = nblk * 8;
    const int sj   = j0 >> 5;
    const int hbj  = (j0 >> 4) & 1;
    const int inj  = (j0 & 15) * 2;

    // phase p: L0 computes step p (p<T); L1 computes step p-2 (p>=2).
    for (int p = 0; p <= T_STEPS + 1; ++p) {
        const bool actL0 = (layer == 0) && (p < T_STEPS);
        const bool actL1 = (layer == 1) && (p >= 2);
        const bool active = actL0 || actL1;

        float px[16];
        v16i ahh = zero16(), amid = zero16();

        // ---- pre-poll work ------------------------------------------------
        if (actL0) {
            // x-projection for step p (no cross-WG dependency)
            v16i ax = zero16(), mx = zero16();
            const short* axp = xq + ((size_t)mrow * 512 + p) * 256 + ksub;
#pragma unroll
            for (int s = 0; s < 8; ++s)
                kstep(axp + s * 32, wlds + s * 2048 + lane * 16, ax, mx);
#pragma unroll
            for (int r = 0; r < 16; ++r)
                px[r] = ((float)ax[r] * 65536.f + (float)mx[r] * 256.f) * inv30;
        } else if (actL1) {
            // pre-guard: h0(p-2) visible once all L0 slots >= p-1 (L0 posts
            // value q+1 after storing h0(q); normally pre-satisfied).
            if (tid < 32) {
                const unsigned thr = (unsigned)(p - 1);
                const unsigned* sp = gslots + tid * 4;
                for (;;) {
                    v4i v = ld4_mall(sp);
                    bool ok = ((unsigned)v.x >= thr) && ((unsigned)v.y >= thr) &&
                              ((unsigned)v.z >= thr) && ((unsigned)v.w >= thr);
                    if (!__ballot(!ok)) break;
                    __builtin_amdgcn_s_sleep(3);
                }
            }
            __syncthreads();
            asm volatile("" ::: "memory");
            // hoisted h0(p-2) stream (weight ksteps 0..31)
            const char* f0 = (const char*)h0q + ((p - 2) & 7) * 131072
                           + RB * 65536 + lane * 32;
            v4i b0[16], b1[16];
            waitcnt0();
            const char* W = wlds + lane * 16;
            load_f16_nw(f0, b0);
            load_f16_nw(f0 + 16384, b1);
            WAIT_BIND("16", b0); consume8(b0, W, ahh, amid);
            load_f16_nw(f0 + 32768, b0);
            WAIT_BIND("16", b1); consume8(b1, W + 8 * 2048, ahh, amid);
            load_f16_nw(f0 + 49152, b1);
            WAIT_BIND("16", b0); consume8(b0, W + 16 * 2048, ahh, amid);
            WAIT_BIND("0", b1);  consume8(b1, W + 24 * 2048, ahh, amid);
        }

        // ---- one-hop subset poll (gen p) ----------------------------------
        // L0: lanes 0-31 poll L0 slots >= p (RAW h0(p-1));
        //     lanes 32-63 poll L1 slots >= p-5 (WAR lag-guard, h0 ring=8).
        // L1: lanes 0-63 poll L1 slots >= p (RAW h2(p-3); WAR implied).
        if (p > 0) {
            if (tid < 64) {
                unsigned thr;
                const unsigned* sp;
                if (layer == 0) {
                    sp  = gslots + tid * 4;            // slots 0..255
                    thr = (tid < 32) ? (unsigned)p
                                     : (unsigned)(p > 5 ? p - 5 : 0);
                } else {
                    sp  = gslots + 128 + (tid & 31) * 4;  // L1 slots 128..255
                    thr = (unsigned)p;
                }
                for (;;) {
                    v4i v = ld4_mall(sp);
                    bool ok = ((unsigned)v.x >= thr) && ((unsigned)v.y >= thr) &&
                              ((unsigned)v.z >= thr) && ((unsigned)v.w >= thr);
                    if (!__ballot(!ok)) break;
                    __builtin_amdgcn_s_sleep(3);
                }
            }
            __syncthreads();
            asm volatile("" ::: "memory");
        }

        if (active) {
            float gates[16];
            v4i b0[16], b1[16];
            if (layer == 0) {
                // h0(p-1) stream (weight ksteps 8..39); h(-1)=0 -> skip at p=0
                if (p > 0) {
                    const char* f0 = (const char*)h0q + ((p - 1) & 7) * 131072
                                   + RB * 65536 + lane * 32;
                    waitcnt0();
                    const char* W = wlds + lane * 16;
                    load_f16_nw(f0, b0);
                    load_f16_nw(f0 + 16384, b1);
                    WAIT_BIND("16", b0); consume8(b0, W + 8 * 2048, ahh, amid);
                    load_f16_nw(f0 + 32768, b0);
                    WAIT_BIND("16", b1); consume8(b1, W + 16 * 2048, ahh, amid);
                    load_f16_nw(f0 + 49152, b1);
                    WAIT_BIND("16", b0); consume8(b0, W + 24 * 2048, ahh, amid);
                    WAIT_BIND("0", b1);  consume8(b1, W + 32 * 2048, ahh, amid);
                }
#pragma unroll
                for (int r = 0; r < 16; ++r)
                    gates[r] = px[r]
                             + ((float)ahh[r] * 65536.f + (float)amid[r] * 256.f) * inv33
                             + offs[lane & 31];
            } else {
                // h2(p-3) stream (weight ksteps 32..63); h2(-1)=0 -> skip p=2
                if (p > 2) {
                    const char* f2 = (const char*)h2q + ((p - 3) & 3) * 131072
                                   + RB * 65536 + lane * 32;
                    waitcnt0();
                    const char* W = wlds + lane * 16;
                    load_f16_nw(f2, b0);
                    load_f16_nw(f2 + 16384, b1);
                    WAIT_BIND("16", b0); consume8(b0, W + 32 * 2048, ahh, amid);
                    load_f16_nw(f2 + 32768, b0);
                    WAIT_BIND("16", b1); consume8(b1, W + 40 * 2048, ahh, amid);
                    load_f16_nw(f2 + 49152, b1);
                    WAIT_BIND("16", b0); consume8(b0, W + 48 * 2048, ahh, amid);
                    WAIT_BIND("0", b1);  consume8(b1, W + 56 * 2048, ahh, amid);
                }
#pragma unroll
                for (int r = 0; r < 16; ++r)
                    gates[r] = ((float)ahh[r] * 65536.f + (float)amid[r] * 256.f) * inv33
                             + offs[lane & 31];
            }
            // scatter C/D frag to LDS: col=lane&31, row=(r&3)+8*(r>>2)+4*(lane>>5)
            {
                const int rbase = RB * 32 + 4 * (lane >> 5);
                const int c = lane & 31;
#pragma unroll
                for (int r = 0; r < 16; ++r) {
                    int row = rbase + (r & 3) + 8 * (r >> 2);
                    gbuf[row * 33 + c] = gates[r];
                }
            }
        }
        __syncthreads();
        if (active && tid < 64) {
            // state update: thread = row, all 8 units; ONE 16B fragment store.
            const int r = tid;
            unsigned hq[8];
            float hf[8];
#pragma unroll
            for (int u = 0; u < 8; ++u) {
                const float gi = gbuf[r * 33 + 4 * u + 0];
                const float gf = gbuf[r * 33 + 4 * u + 1];
                const float gg = gbuf[r * 33 + 4 * u + 2];
                const float go = gbuf[r * 33 + 4 * u + 3];
                const float i_ = 1.f / (1.f + __expf(-gi));
                const float f_ = 1.f / (1.f + __expf(-gf));
                const float g_ = 1.f - 2.f / (__expf(2.f * gg) + 1.f);
                const float o_ = 1.f / (1.f + __expf(-go));
                float c_ = f_ * cbuf[r * 9 + u] + i_ * g_;
                cbuf[r * 9 + u] = c_;
                const float h_ = o_ * (1.f - 2.f / (__expf(2.f * c_) + 1.f));
                hq[u] = (unsigned)(unsigned short)(short)__float2int_rn(h_ * 16384.f);
                hf[u] = h_;
            }
            v4i pk;
            pk.x = (int)(hq[0] | (hq[1] << 16));
            pk.y = (int)(hq[2] | (hq[3] << 16));
            pk.z = (int)(hq[4] | (hq[5] << 16));
            pk.w = (int)(hq[6] | (hq[7] << 16));
            // L0 writes h0(p) slot p&7; L1 writes h2(p-2) slot (p-2)&3
            char* hw = (layer == 0)
                     ? (char*)h0q + (p & 7) * 131072
                     : (char*)h2q + ((p - 2) & 3) * 131072;
            hw += (r >> 5) * 65536 + sj * 2048 + ((r & 31) + 32 * hbj) * 32 + inj;
            st16_wt(hw, pk);
            if (layer == 1 && p == T_STEPS + 1) {
#pragma unroll
                for (int u = 0; u < 8; ++u) h2f[r * 1024 + j0 + u] = hf[u];
            }
        }
        // ---- arrival (value p+1, release: h stores drained first) ---------
        if (p < T_STEPS + 1) {
            waitcnt0();
            __syncthreads();
            if (tid == 0)
                store_slot(gslots + wg, (unsigned)(p + 1));
        }
    }
}

// ---------------------------------------------------------------------------
__global__ void final_lin(const float* __restrict__ h2f, const float* __restrict__ wlin,
                          const float* __restrict__ blin, float* __restrict__ out)
{
    const int b = blockIdx.x;
    const int l = threadIdx.x;
    float s = 0.f;
    for (int j = l; j < 1024; j += 64) s += h2f[b * 1024 + j] * wlin[j];
#pragma unroll
    for (int off = 32; off; off >>= 1) s += __shfl_down(s, off);
    if (l == 0) out[b] = s + blin[0];
}

// ---------------------------------------------------------------------------
extern "C" void kernel_launch(void* const* d_in, const int* in_sizes, int n_in,
                              void* d_out, int out_size, void* d_ws, size_t ws_size,
                              hipStream_t stream)
{
    const float* x    = (const float*)d_in[0];
    const float* wih0 = (const float*)d_in[1];
    const float* whh0 = (const float*)d_in[2];
    const float* bih0 = (const float*)d_in[3];
    const float* bhh0 = (const float*)d_in[4];
    const float* wih1 = (const float*)d_in[5];
    const float* whh1 = (const float*)d_in[6];
    const float* bih1 = (const float*)d_in[7];
    const float* bhh1 = (const float*)d_in[8];
    const float* wlin = (const float*)d_in[9];
    const float* blin = (const float*)d_in[10];

    // workspace layout
    char* ws = (char*)d_ws;
    unsigned* gslots = (unsigned*)ws;                    // 256 x 4B packed (16 lines)
    short* h0q = (short*)(ws + 65536);                   // [8 slots][128KB] fragment ring
    short* h2q = (short*)(ws + 65536 + 1048576);         // [4 slots][128KB] fragment ring
    float* h2f = (float*)(ws + 65536 + 1572864);         // [64][1024] f32 = 256KB
    short* xq  = (short*)(ws + 65536 + 1835008);         // 16MB
    char*  wimg = ws + 65536 + 1835008 + 16777216;       // 256 * 128KB = 32MB

    // zero arrival slots (h rings are written before any read)
    hipMemsetAsync(ws, 0, 65536, stream);

    quant_x<<<32768, 256, 0, stream>>>(x, xq, 64 * 512 * 256);
    quant_w<<<4096, 256, 0, stream>>>(wih0, whh0, wih1, whh1, wimg);

    hipFuncSetAttribute((const void*)lstm_main,
        hipFuncAttributeMaxDynamicSharedMemorySize, SMEM_BYTES);

    lstm_main<<<NWG, 128, SMEM_BYTES, stream>>>(xq, wimg, bih0, bhh0, bih1, bhh1,
                                                h0q, h2q, h2f, gslots);
    final_lin<<<64, 64, 0, stream>>>(h2f, wlin, blin, (float*)d_out);
}